// Round 3
// baseline (641.009 us; speedup 1.0000x reference)
//
#include <hip/hip_runtime.h>
#include <cstddef>

// DeformLayer on MI355X. Round 6:
//  - deconv rebuilt barrier-free: y materialized once as halo-padded NHWC bf16
//    (yt[b][66][66][256]) by k_tr_y; with K ordered [tap][ci_l] every B-frag is
//    a contiguous 16B global load. No LDS, no barriers, no pack VALU in the
//    GEMM: per iter = 4 A-frag + 4 B-frag loads + 16 MFMA. Full 256-o blocks
//    (grid 2048), acc[4][4], launch_bounds(256,4).
//  - deform keeps R5 pipeline; bfr-pack replaced by native __bf16 casts
//    (v_cvt_pk_bf16_f32, same RNE bits, ~25 fewer VALU/iter).
//  - ws: yt (17.8 MB) overlays om/wofft/cpk/Wdb (dead by k_tr_y); total 19.9 MB.

#define B_EPS 1e-5f

typedef __bf16 bf16x8 __attribute__((ext_vector_type(8)));
typedef float f32x4 __attribute__((ext_vector_type(4)));
typedef unsigned short u16;
typedef unsigned int u32;

__device__ __forceinline__ u32 bfr(float f) {          // fp32 -> bf16 bits (RNE)
    u32 u = __float_as_uint(f);
    return (u + 0x7FFFu + ((u >> 16) & 1u)) >> 16;
}

// gather 4 bilinear corners x 8 channels (2x f32x4 each) for one pixel/subgroup
__device__ __forceinline__ void gather8(const float* cb2, uint4 q, int g8, f32x4* ga) {
    const float* p00 = cb2 + ((size_t)(q.x & 0xFFFFu) << 5) + g8;
    const float* p01 = cb2 + ((size_t)(q.x >> 16) << 5) + g8;
    const float* p10 = cb2 + ((size_t)(q.y & 0xFFFFu) << 5) + g8;
    const float* p11 = cb2 + ((size_t)(q.y >> 16) << 5) + g8;
    ga[0] = *(const f32x4*)p00; ga[1] = *(const f32x4*)(p00 + 4);
    ga[2] = *(const f32x4*)p01; ga[3] = *(const f32x4*)(p01 + 4);
    ga[4] = *(const f32x4*)p10; ga[5] = *(const f32x4*)(p10 + 4);
    ga[6] = *(const f32x4*)p11; ga[7] = *(const f32x4*)(p11 + 4);
}

// combine corners with packed bf16 weights -> 8 bf16 values as uint4
__device__ __forceinline__ uint4 packv(uint4 q, const f32x4* ga) {
    const float w00 = __uint_as_float(q.z << 16);
    const float w01 = __uint_as_float(q.z & 0xFFFF0000u);
    const float w10 = __uint_as_float(q.w << 16);
    const float w11 = __uint_as_float(q.w & 0xFFFF0000u);
    union { bf16x8 h; uint4 u; } r;
#pragma unroll
    for (int jj = 0; jj < 4; ++jj) {
        r.h[jj]     = (__bf16)fmaf(w00, ga[0][jj], fmaf(w01, ga[2][jj], fmaf(w10, ga[4][jj], w11 * ga[6][jj])));
        r.h[4 + jj] = (__bf16)fmaf(w00, ga[1][jj], fmaf(w01, ga[3][jj], fmaf(w10, ga[5][jj], w11 * ga[7][jj])));
    }
    return r.u;
}

// ---------------- tiny prep kernels ----------------
// w_off[27][256][9] -> wofft[c][co*9+t] (uniform scalar loads in offset conv)
__global__ __launch_bounds__(256) void k_tr_woff(const float* __restrict__ w,
                                                 float* __restrict__ o) {
    int i = blockIdx.x * 256 + threadIdx.x;      // 62208
    int t9 = i % 9; int r = i / 9; int c = r & 255; int co = r >> 8;
    o[c * 243 + co * 9 + t9] = w[i];
}

// w_dcn[o][c][9] -> Wdb[ch][oc][32] bf16 (unpadded, frag-direct), ch = k*8+cc
__global__ __launch_bounds__(256) void k_prep_wdb(const float* __restrict__ w,
                                                  u16* __restrict__ o) {
    int i = blockIdx.x * 256 + threadIdx.x;      // 589824 = 2304*256
    int kk = i & 31; int e = i >> 5;
    int oc = e & 255; int ch = e >> 8;
    int cc = ch & 7; int k = ch >> 3;
    o[i] = (u16)bfr(w[oc * 2304 + (cc * 32 + kk) * 9 + k]);
}

// w_up[ci][co][wr][wc] -> Wtb[cls][cc][oc][32kk] bf16, kk = tap*8 + ci_l
__global__ __launch_bounds__(256) void k_prep_wtb(const float* __restrict__ w,
                                                  u16* __restrict__ o) {
    int i = blockIdx.x * 256 + threadIdx.x;      // 1048576 = 4096*256
    int kk = i & 31; int e = i >> 5;
    int oc = e & 255; e >>= 8;
    int cc = e & 31; int cls = e >> 5;
    int tap = kk >> 3, ci = cc * 8 + (kk & 7);
    int ca = cls >> 1, cb = cls & 1;
    int wr = (tap >> 1) ? (ca ? 0 : 1) : (ca ? 2 : 3);
    int wc = (tap & 1) ? (cb ? 0 : 1) : (cb ? 2 : 3);
    o[i] = (u16)bfr(w[ci * 4096 + oc * 16 + wr * 4 + wc]);
}

// folded BN params: bnp = [sc1|bi1|sc2|bi2], 4x256 floats
__global__ __launch_bounds__(256) void k_bn_prep(
    const float* g1, const float* be1, const float* mu1, const float* va1,
    const float* g2, const float* be2, const float* mu2, const float* va2,
    float* bnp) {
    int t = threadIdx.x;
    float s1 = g1[t] * rsqrtf(va1[t] + B_EPS);
    bnp[t] = s1; bnp[256 + t] = be1[t] - mu1[t] * s1;
    float s2 = g2[t] * rsqrtf(va2[t] + B_EPS);
    bnp[512 + t] = s2; bnp[768 + t] = be2[t] - mu2[t] * s2;
}

// om init: om[b][27][4096] = b_off[co]  (atomic accumulation base)
__global__ __launch_bounds__(256) void k_om_init(const float* __restrict__ b_off,
                                                 float* __restrict__ om) {
    int i = blockIdx.x * 256 + threadIdx.x;      // 884736 = 3456*256
    int co = (i >> 12) % 27;
    om[i] = b_off[co];
}

// x[b][c][4096] -> xt[b][cc][pix][cl]  (fp32 chunk-NHWC, cc = c/32, cl = c%32)
__global__ __launch_bounds__(256) void k_tr_x(const float* __restrict__ x,
                                              float* __restrict__ xt) {
    const int t = threadIdx.x;
    const int pg = blockIdx.x & 15;              // 256-pixel group
    const int cc = (blockIdx.x >> 4) & 7;
    const int b = blockIdx.x >> 7;               // grid 1024
    const int pix = (pg << 8) + t;
    const float* xp = x + ((size_t)b << 20) + ((size_t)(cc << 5) << 12) + pix;
    float v[32];
#pragma unroll
    for (int cl = 0; cl < 32; ++cl) v[cl] = xp[(size_t)cl << 12];
    float* op = xt + ((size_t)b << 20) + ((size_t)cc << 17) + ((size_t)pix << 5);
#pragma unroll
    for (int i = 0; i < 8; ++i)
        *(f32x4*)(op + i * 4) = *(const f32x4*)&v[i * 4];
}

// y[b][o][4096] -> yt[b][66][66][256] bf16 halo-padded NHWC (zeros on border)
__global__ __launch_bounds__(256) void k_tr_y(const float* __restrict__ y,
                                              u16* __restrict__ yt) {
    const int t = threadIdx.x;
    const int blk = blockIdx.x % 18;
    const int oc = (blockIdx.x / 18) & 7;
    const int b = blockIdx.x / 144;              // grid 1152
    const int hp = blk * 256 + t;
    if (hp >= 4356) return;
    const int h = hp / 66, w = hp % 66;
    u16* dst = yt + ((size_t)b * 4356 + hp) * 256 + oc * 32;
    if (h == 0 || h == 65 || w == 0 || w == 65) {
        uint4 z = make_uint4(0, 0, 0, 0);
#pragma unroll
        for (int i = 0; i < 4; ++i) *(uint4*)(dst + i * 8) = z;
        return;
    }
    const float* yp = y + ((size_t)b << 20) + ((size_t)(oc * 32) << 12)
                    + ((h - 1) << 6) + (w - 1);
    u16 vv[32];
#pragma unroll
    for (int cl = 0; cl < 32; ++cl) vv[cl] = (u16)bfr(yp[(size_t)cl << 12]);
#pragma unroll
    for (int i = 0; i < 4; ++i) *(uint4*)(dst + i * 8) = *(const uint4*)&vv[i * 8];
}

// ---------------- offset conv partial: 8 c-chunks, atomicAdd into om ---------
__global__ __launch_bounds__(256) void k_offset_conv_part(
    const float* __restrict__ x, const float* __restrict__ wofft,
    float* __restrict__ om)
{
    const int t = threadIdx.x;
    const int chunk = blockIdx.x & 7;
    const int rg = (blockIdx.x >> 3) & 15;
    const int b = blockIdx.x >> 7;
    const int h = (rg << 2) + (t >> 6);
    const int w = t & 63;
    const int c0 = chunk << 5;
    const float* xb = x + ((size_t)b << 20);
    float acc[27];
#pragma unroll
    for (int i = 0; i < 27; ++i) acc[i] = 0.f;
    for (int cl = 0; cl < 32; ++cl) {
        const int c = c0 + cl;
        const float* xc = xb + (c << 12);
        float xv[9];
#pragma unroll
        for (int tr = 0; tr < 3; ++tr) {
            int hh = h + tr - 1;
            bool vy = (unsigned)hh < 64u;
#pragma unroll
            for (int tc = 0; tc < 3; ++tc) {
                int ww = w + tc - 1;
                xv[tr * 3 + tc] = (vy && (unsigned)ww < 64u) ? xc[(hh << 6) + ww] : 0.f;
            }
        }
        const float* wc = wofft + c * 243;
#pragma unroll
        for (int co = 0; co < 27; ++co)
#pragma unroll
            for (int k = 0; k < 9; ++k)
                acc[co] = fmaf(xv[k], wc[co * 9 + k], acc[co]);
    }
    float* omb = om + (size_t)b * 110592 + (h << 6) + w;
#pragma unroll
    for (int co = 0; co < 27; ++co)
        atomicAdd(&omb[co << 12], acc[co]);
}

// ---------------- bilinear coeff prep (packed: 4x u16 idx + 4x bf16 wgt) ------
__global__ __launch_bounds__(256) void k_prep_coeff(
    const float* __restrict__ om, uint4* __restrict__ cpk)
{
    int i = blockIdx.x * 256 + threadIdx.x;      // 294912
    int pix = i & 4095;
    int bk = i >> 12;
    int k = bk % 9;
    int b = bk / 9;
    int h = pix >> 6, w = pix & 63;
    const float* omb = om + (size_t)b * 110592;
    float dy = omb[(k << 12) + pix];
    float dx = omb[((9 + k) << 12) + pix];
    float mr = omb[((18 + k) << 12) + pix];
    float m  = 1.f / (1.f + __expf(-mr));
    float py = dy + (float)(k / 3 - 1 + h);
    float px = dx + (float)(k % 3 - 1 + w);
    float y0f = floorf(py), x0f = floorf(px);
    float wy = py - y0f, wx = px - x0f;
    int y0 = (int)y0f, x0 = (int)x0f;
    int y1 = y0 + 1, x1 = x0 + 1;
    float vy0 = ((unsigned)y0 < 64u) ? 1.f : 0.f;
    float vy1 = ((unsigned)y1 < 64u) ? 1.f : 0.f;
    float vx0 = ((unsigned)x0 < 64u) ? 1.f : 0.f;
    float vx1 = ((unsigned)x1 < 64u) ? 1.f : 0.f;
    int cy0 = min(max(y0, 0), 63), cy1 = min(max(y1, 0), 63);
    int cx0 = min(max(x0, 0), 63), cx1 = min(max(x1, 0), 63);
    u32 xw = (u32)((cy0 << 6) + cx0) | ((u32)((cy0 << 6) + cx1) << 16);
    u32 yw = (u32)((cy1 << 6) + cx0) | ((u32)((cy1 << 6) + cx1) << 16);
    float w00 = m * (1.f - wy) * (1.f - wx) * vy0 * vx0;
    float w01 = m * (1.f - wy) * wx         * vy0 * vx1;
    float w10 = m * wy         * (1.f - wx) * vy1 * vx0;
    float w11 = m * wy         * wx         * vy1 * vx1;
    u32 zw = bfr(w00) | (bfr(w01) << 16);
    u32 ww2 = bfr(w10) | (bfr(w11) << 16);
    cpk[i] = make_uint4(xw, yw, zw, ww2);
}

// ---------------- deform conv MFMA GEMM + BN1 + ReLU -> y ----------------
// No sA: A-frags loaded global->reg (prefetched one chunk ahead). LDS = sB x2.
// One barrier per K-chunk; gathers + A prefetch issued before MFMA.
__global__ __launch_bounds__(256, 2) void k_deform_mfma(
    const float* __restrict__ xt, const u16* __restrict__ Wdb,
    const uint4* __restrict__ cpk, const float* __restrict__ bnp,
    float* __restrict__ yout)
{
    __shared__ __align__(16) u16 sB[2][64 * 40];
    const int t = threadIdx.x;
    const int row = blockIdx.x & 63;
    const int b = blockIdx.x >> 6;               // grid 512
    const int pix0 = row << 6;
    const int p = t >> 2;        // gather pixel 0..63
    const int g = t & 3;         // c subgroup (8 channels each)
    const int g8 = g << 3;
    const float* xtb = xt + ((size_t)b << 20);   // [cc][4096][32]

    const int lane = t & 63;
    const int wv = t >> 6;
    const int quad = lane >> 4;
    const int ln = lane & 15;
    // per-thread A-frag base: row (wv*64 + mi*16 + ln), k-cols quad*8..+7
    const u16* Wrow = Wdb + (size_t)(wv * 64 + ln) * 32 + quad * 8;

    f32x4 acc[4][4];
#pragma unroll
    for (int i = 0; i < 4; ++i)
#pragma unroll
        for (int j = 0; j < 4; ++j) acc[i][j] = (f32x4)0.f;

    bf16x8 afb[2][4];
    uint4 qcur = cpk[(size_t)(b * 9) * 4096 + pix0 + p];
    {   // prologue: A frags + gather for ch=0 into parity 0
#pragma unroll
        for (int mi = 0; mi < 4; ++mi)
            afb[0][mi] = *(const bf16x8*)(Wrow + mi * 512);
        f32x4 ga[8];
        gather8(xtb, qcur, g8, ga);
        *(uint4*)&sB[0][p * 40 + g8] = packv(qcur, ga);
        __syncthreads();
    }

    for (int k = 0; k < 9; ++k) {
        uint4 qnext = qcur;
        if (k < 8) qnext = cpk[(size_t)(b * 9 + k + 1) * 4096 + pix0 + p];
#pragma unroll
        for (int cc = 0; cc < 8; ++cc) {
            const int ch = k * 8 + cc;
            const int par = cc & 1;
            const bool pre = ch < 71;
            const uint4 q = (cc == 7) ? qnext : qcur;   // static select (unrolled)
            f32x4 ga[8];
            if (pre) {
                // prefetch next A frags (coalesced 16B/lane from L2-hot Wdb)
                const u16* Wn = Wrow + (size_t)(ch + 1) * 8192;
#pragma unroll
                for (int mi = 0; mi < 4; ++mi)
                    afb[par ^ 1][mi] = *(const bf16x8*)(Wn + mi * 512);
                // issue next-iter gathers
                gather8(xtb + ((size_t)((cc + 1) & 7) << 17), q, g8, ga);
            }
            // MFMA on current parity
            bf16x8 bg[4];
#pragma unroll
            for (int i = 0; i < 4; ++i)
                bg[i] = *(const bf16x8*)&sB[par][(i * 16 + ln) * 40 + quad * 8];
#pragma unroll
            for (int mi = 0; mi < 4; ++mi)
#pragma unroll
                for (int ni = 0; ni < 4; ++ni)
                    acc[mi][ni] = __builtin_amdgcn_mfma_f32_16x16x32_bf16(
                        afb[par][mi], bg[ni], acc[mi][ni], 0, 0, 0);
            if (pre)
                *(uint4*)&sB[par ^ 1][p * 40 + g8] = packv(q, ga);
            __syncthreads();
        }
        qcur = qnext;
    }

    const float* sc1 = bnp;
    const float* bi1 = bnp + 256;
    float* yb2 = yout + ((size_t)b << 20);
#pragma unroll
    for (int mi = 0; mi < 4; ++mi) {
#pragma unroll
        for (int r = 0; r < 4; ++r) {
            int o = wv * 64 + mi * 16 + quad * 4 + r;
            float sc = sc1[o], bi = bi1[o];
#pragma unroll
            for (int ni = 0; ni < 4; ++ni) {
                float v = fmaxf(fmaf(acc[mi][ni][r], sc, bi), 0.f);
                yb2[((size_t)o << 12) + pix0 + ni * 16 + ln] = v;
            }
        }
    }
}

// ---------------- deconv MFMA GEMM + BN2 + ReLU -> up ----------------
// Barrier-free, LDS-free: A and B frags are direct contiguous 16B global
// loads (B from halo'd NHWC bf16 yt). 16 MFMA + 8 loads per iter per wave.
__global__ __launch_bounds__(256, 4) void k_deconv_mfma(
    const u16* __restrict__ yt, const u16* __restrict__ Wtb,
    const float* __restrict__ bnp, float* __restrict__ up)
{
    const int t = threadIdx.x;
    const int h0 = blockIdx.x & 63;
    const int cls = (blockIdx.x >> 6) & 3;
    const int b = blockIdx.x >> 8;               // grid 2048
    const int ca = cls >> 1, cb = cls & 1;
    const int DH0 = ca ? 0 : -1, DH1 = ca ? 1 : 0;
    const int DW0 = cb ? 0 : -1, DW1 = cb ? 1 : 0;

    const int lane = t & 63;
    const int wv = t >> 6;
    const int quad = lane >> 4;
    const int ln = lane & 15;

    // this thread's tap is its quad (K order = [tap][ci_l])
    const int DHq = (quad >> 1) ? DH1 : DH0;
    const int DWq = (quad & 1) ? DW1 : DW0;

    const u16* ytb = yt + (size_t)b * (4356 * 256);
    const u16* Bb[4];
#pragma unroll
    for (int i = 0; i < 4; ++i) {
        int pix = i * 16 + ln;
        Bb[i] = ytb + ((size_t)((h0 + DHq + 1) * 66 + (pix + DWq + 1)) << 8);
    }
    const u16* Ab = Wtb + (size_t)(cls * 32) * 8192
                  + (size_t)(wv * 64 + ln) * 32 + quad * 8;

    f32x4 acc[4][4];
#pragma unroll
    for (int i = 0; i < 4; ++i)
#pragma unroll
        for (int j = 0; j < 4; ++j) acc[i][j] = (f32x4)0.f;

#pragma unroll 2
    for (int cc = 0; cc < 32; ++cc) {
        bf16x8 af[4], bg[4];
#pragma unroll
        for (int mi = 0; mi < 4; ++mi)
            af[mi] = *(const bf16x8*)(Ab + (size_t)cc * 8192 + mi * 512);
#pragma unroll
        for (int i = 0; i < 4; ++i)
            bg[i] = *(const bf16x8*)(Bb[i] + cc * 8);
#pragma unroll
        for (int mi = 0; mi < 4; ++mi)
#pragma unroll
            for (int ni = 0; ni < 4; ++ni)
                acc[mi][ni] = __builtin_amdgcn_mfma_f32_16x16x32_bf16(
                    af[mi], bg[ni], acc[mi][ni], 0, 0, 0);
    }

    const float* sc2 = bnp + 512;
    const float* bi2 = bnp + 768;
    float* ub = up + ((size_t)b << 22);
    const int pr = (h0 << 1) + ca;
#pragma unroll
    for (int mi = 0; mi < 4; ++mi) {
#pragma unroll
        for (int r = 0; r < 4; ++r) {
            int o = wv * 64 + mi * 16 + quad * 4 + r;
            float sc = sc2[o], bi = bi2[o];
#pragma unroll
            for (int ni = 0; ni < 4; ++ni) {
                int qc = ((ni * 16 + ln) << 1) + cb;
                float v = fmaxf(fmaf(acc[mi][ni][r], sc, bi), 0.f);
                ub[((size_t)o << 14) + (pr << 7) + qc] = v;
            }
        }
    }
}

extern "C" void kernel_launch(void* const* d_in, const int* in_sizes, int n_in,
                              void* d_out, int out_size, void* d_ws, size_t ws_size,
                              hipStream_t stream)
{
    const float* x     = (const float*)d_in[0];
    const float* w_off = (const float*)d_in[1];
    const float* b_off = (const float*)d_in[2];
    const float* w_dcn = (const float*)d_in[3];
    const float* g1    = (const float*)d_in[4];
    const float* be1   = (const float*)d_in[5];
    const float* mu1   = (const float*)d_in[6];
    const float* va1   = (const float*)d_in[7];
    const float* w_up  = (const float*)d_in[8];
    const float* g2    = (const float*)d_in[9];
    const float* be2   = (const float*)d_in[10];
    const float* mu2   = (const float*)d_in[11];
    const float* va2   = (const float*)d_in[12];

    float* yout = (float*)d_out;                 // 8*256*64*64
    float* up   = (float*)d_out + 8388608;       // 8*256*128*128
    // xt scratch lives in the 'up' region (33.5 MB of its 134 MB); consumed by
    // k_deform_mfma, later fully overwritten by k_deconv_mfma.
    float* xt   = up;

    // ws layout: region0 (0..17,842,176) holds phase-A buffers (om, wofft,
    // cpk, Wdb — all dead after k_deform_mfma), then is overlaid by yt
    // (halo'd NHWC bf16 y) for phase B. Wtb+bnp live past both phases.
    char* ws = (char*)d_ws;
    float* om    = (float*)(ws + 0);             // 3,538,944 B
    float* wofft = (float*)(ws + 3538944);       //   248,832 B
    uint4* cpk   = (uint4*)(ws + 3787776);       // 4,718,592 B
    u16*   Wdb   = (u16*)  (ws + 8506368);       // 1,179,648 B -> ends 9,686,016
    u16*   yt    = (u16*)  (ws + 0);             // 17,842,176 B (phase B overlay)
    u16*   Wtb   = (u16*)  (ws + 17842176);      // 2,097,152 B
    float* bnp   = (float*)(ws + 19939328);      //     4,096 B
    // total ws: 19,943,424 B (~19.9 MB)

    k_tr_woff   <<<243,  256, 0, stream>>>(w_off, wofft);
    k_prep_wdb  <<<2304, 256, 0, stream>>>(w_dcn, Wdb);
    k_prep_wtb  <<<4096, 256, 0, stream>>>(w_up, Wtb);
    k_bn_prep   <<<1,    256, 0, stream>>>(g1, be1, mu1, va1, g2, be2, mu2, va2, bnp);
    k_om_init   <<<3456, 256, 0, stream>>>(b_off, om);
    k_tr_x      <<<1024, 256, 0, stream>>>(x, xt);
    k_offset_conv_part<<<1024, 256, 0, stream>>>(x, wofft, om);
    k_prep_coeff<<<1152, 256, 0, stream>>>(om, cpk);
    k_deform_mfma<<<512, 256, 0, stream>>>(xt, Wdb, cpk, bnp, yout);
    k_tr_y      <<<1152, 256, 0, stream>>>(yout, yt);
    k_deconv_mfma<<<2048,256, 0, stream>>>(yt, Wtb, bnp, up);
}

// Round 4
// 561.082 us; speedup vs baseline: 1.1425x; 1.1425x over previous
//
#include <hip/hip_runtime.h>
#include <cstddef>

// DeformLayer on MI355X. Round 7: fix deconv VMEM scatter. R6 counters
// (VALU 6%, Mfma 13.6%, BW 15%, conflicts 0) => bound by per-line TA
// serialization: yt[pix][256ci] put quad-lanes 512B apart -> ~64 lines per
// B-frag load. New layout yt[b][cg=ci/8][66*66][8ci]: lane's 16B frag stays
// contiguous AND consecutive lanes are contiguous -> 4x256B segments/load.
// k_tr_y emits 4 plane-strided coalesced streams. Everything else unchanged.

#define B_EPS 1e-5f

typedef __bf16 bf16x8 __attribute__((ext_vector_type(8)));
typedef float f32x4 __attribute__((ext_vector_type(4)));
typedef unsigned short u16;
typedef unsigned int u32;

__device__ __forceinline__ u32 bfr(float f) {          // fp32 -> bf16 bits (RNE)
    u32 u = __float_as_uint(f);
    return (u + 0x7FFFu + ((u >> 16) & 1u)) >> 16;
}

// gather 4 bilinear corners x 8 channels (2x f32x4 each) for one pixel/subgroup
__device__ __forceinline__ void gather8(const float* cb2, uint4 q, int g8, f32x4* ga) {
    const float* p00 = cb2 + ((size_t)(q.x & 0xFFFFu) << 5) + g8;
    const float* p01 = cb2 + ((size_t)(q.x >> 16) << 5) + g8;
    const float* p10 = cb2 + ((size_t)(q.y & 0xFFFFu) << 5) + g8;
    const float* p11 = cb2 + ((size_t)(q.y >> 16) << 5) + g8;
    ga[0] = *(const f32x4*)p00; ga[1] = *(const f32x4*)(p00 + 4);
    ga[2] = *(const f32x4*)p01; ga[3] = *(const f32x4*)(p01 + 4);
    ga[4] = *(const f32x4*)p10; ga[5] = *(const f32x4*)(p10 + 4);
    ga[6] = *(const f32x4*)p11; ga[7] = *(const f32x4*)(p11 + 4);
}

// combine corners with packed bf16 weights -> 8 bf16 values as uint4
__device__ __forceinline__ uint4 packv(uint4 q, const f32x4* ga) {
    const float w00 = __uint_as_float(q.z << 16);
    const float w01 = __uint_as_float(q.z & 0xFFFF0000u);
    const float w10 = __uint_as_float(q.w << 16);
    const float w11 = __uint_as_float(q.w & 0xFFFF0000u);
    union { bf16x8 h; uint4 u; } r;
#pragma unroll
    for (int jj = 0; jj < 4; ++jj) {
        r.h[jj]     = (__bf16)fmaf(w00, ga[0][jj], fmaf(w01, ga[2][jj], fmaf(w10, ga[4][jj], w11 * ga[6][jj])));
        r.h[4 + jj] = (__bf16)fmaf(w00, ga[1][jj], fmaf(w01, ga[3][jj], fmaf(w10, ga[5][jj], w11 * ga[7][jj])));
    }
    return r.u;
}

// ---------------- tiny prep kernels ----------------
// w_off[27][256][9] -> wofft[c][co*9+t] (uniform scalar loads in offset conv)
__global__ __launch_bounds__(256) void k_tr_woff(const float* __restrict__ w,
                                                 float* __restrict__ o) {
    int i = blockIdx.x * 256 + threadIdx.x;      // 62208
    int t9 = i % 9; int r = i / 9; int c = r & 255; int co = r >> 8;
    o[c * 243 + co * 9 + t9] = w[i];
}

// w_dcn[o][c][9] -> Wdb[ch][oc][32] bf16 (unpadded, frag-direct), ch = k*8+cc
__global__ __launch_bounds__(256) void k_prep_wdb(const float* __restrict__ w,
                                                  u16* __restrict__ o) {
    int i = blockIdx.x * 256 + threadIdx.x;      // 589824 = 2304*256
    int kk = i & 31; int e = i >> 5;
    int oc = e & 255; int ch = e >> 8;
    int cc = ch & 7; int k = ch >> 3;
    o[i] = (u16)bfr(w[oc * 2304 + (cc * 32 + kk) * 9 + k]);
}

// w_up[ci][co][wr][wc] -> Wtb[cls][cc][oc][32kk] bf16, kk = tap*8 + ci_l
__global__ __launch_bounds__(256) void k_prep_wtb(const float* __restrict__ w,
                                                  u16* __restrict__ o) {
    int i = blockIdx.x * 256 + threadIdx.x;      // 1048576 = 4096*256
    int kk = i & 31; int e = i >> 5;
    int oc = e & 255; e >>= 8;
    int cc = e & 31; int cls = e >> 5;
    int tap = kk >> 3, ci = cc * 8 + (kk & 7);
    int ca = cls >> 1, cb = cls & 1;
    int wr = (tap >> 1) ? (ca ? 0 : 1) : (ca ? 2 : 3);
    int wc = (tap & 1) ? (cb ? 0 : 1) : (cb ? 2 : 3);
    o[i] = (u16)bfr(w[ci * 4096 + oc * 16 + wr * 4 + wc]);
}

// folded BN params: bnp = [sc1|bi1|sc2|bi2], 4x256 floats
__global__ __launch_bounds__(256) void k_bn_prep(
    const float* g1, const float* be1, const float* mu1, const float* va1,
    const float* g2, const float* be2, const float* mu2, const float* va2,
    float* bnp) {
    int t = threadIdx.x;
    float s1 = g1[t] * rsqrtf(va1[t] + B_EPS);
    bnp[t] = s1; bnp[256 + t] = be1[t] - mu1[t] * s1;
    float s2 = g2[t] * rsqrtf(va2[t] + B_EPS);
    bnp[512 + t] = s2; bnp[768 + t] = be2[t] - mu2[t] * s2;
}

// om init: om[b][27][4096] = b_off[co]  (atomic accumulation base)
__global__ __launch_bounds__(256) void k_om_init(const float* __restrict__ b_off,
                                                 float* __restrict__ om) {
    int i = blockIdx.x * 256 + threadIdx.x;      // 884736 = 3456*256
    int co = (i >> 12) % 27;
    om[i] = b_off[co];
}

// x[b][c][4096] -> xt[b][cc][pix][cl]  (fp32 chunk-NHWC, cc = c/32, cl = c%32)
__global__ __launch_bounds__(256) void k_tr_x(const float* __restrict__ x,
                                              float* __restrict__ xt) {
    const int t = threadIdx.x;
    const int pg = blockIdx.x & 15;              // 256-pixel group
    const int cc = (blockIdx.x >> 4) & 7;
    const int b = blockIdx.x >> 7;               // grid 1024
    const int pix = (pg << 8) + t;
    const float* xp = x + ((size_t)b << 20) + ((size_t)(cc << 5) << 12) + pix;
    float v[32];
#pragma unroll
    for (int cl = 0; cl < 32; ++cl) v[cl] = xp[(size_t)cl << 12];
    float* op = xt + ((size_t)b << 20) + ((size_t)cc << 17) + ((size_t)pix << 5);
#pragma unroll
    for (int i = 0; i < 8; ++i)
        *(f32x4*)(op + i * 4) = *(const f32x4*)&v[i * 4];
}

// y[b][o][4096] -> yt[b][cg=ci/8][66*66][8ci] bf16 halo-padded (zeros on border)
__global__ __launch_bounds__(256) void k_tr_y(const float* __restrict__ y,
                                              u16* __restrict__ yt) {
    const int t = threadIdx.x;
    const int blk = blockIdx.x % 18;
    const int oc = (blockIdx.x / 18) & 7;        // 32-ch group
    const int b = blockIdx.x / 144;              // grid 1152
    const int hp = blk * 256 + t;
    if (hp >= 4356) return;
    const int h = hp / 66, w = hp % 66;
    // this thread covers cg = oc*4 .. oc*4+3, plane stride 4356*8 u16
    u16* dstb = yt + (((size_t)b * 32 + oc * 4) * 4356 + hp) * 8;
    if (h == 0 || h == 65 || w == 0 || w == 65) {
        uint4 z = make_uint4(0, 0, 0, 0);
#pragma unroll
        for (int j = 0; j < 4; ++j)
            *(uint4*)(dstb + (size_t)j * (4356 * 8)) = z;
        return;
    }
    const float* yp = y + ((size_t)b << 20) + ((size_t)(oc * 32) << 12)
                    + ((h - 1) << 6) + (w - 1);
    u16 vv[32];
#pragma unroll
    for (int cl = 0; cl < 32; ++cl) vv[cl] = (u16)bfr(yp[(size_t)cl << 12]);
#pragma unroll
    for (int j = 0; j < 4; ++j)
        *(uint4*)(dstb + (size_t)j * (4356 * 8)) = *(const uint4*)&vv[j * 8];
}

// ---------------- offset conv partial: 8 c-chunks, atomicAdd into om ---------
__global__ __launch_bounds__(256) void k_offset_conv_part(
    const float* __restrict__ x, const float* __restrict__ wofft,
    float* __restrict__ om)
{
    const int t = threadIdx.x;
    const int chunk = blockIdx.x & 7;
    const int rg = (blockIdx.x >> 3) & 15;
    const int b = blockIdx.x >> 7;
    const int h = (rg << 2) + (t >> 6);
    const int w = t & 63;
    const int c0 = chunk << 5;
    const float* xb = x + ((size_t)b << 20);
    float acc[27];
#pragma unroll
    for (int i = 0; i < 27; ++i) acc[i] = 0.f;
    for (int cl = 0; cl < 32; ++cl) {
        const int c = c0 + cl;
        const float* xc = xb + (c << 12);
        float xv[9];
#pragma unroll
        for (int tr = 0; tr < 3; ++tr) {
            int hh = h + tr - 1;
            bool vy = (unsigned)hh < 64u;
#pragma unroll
            for (int tc = 0; tc < 3; ++tc) {
                int ww = w + tc - 1;
                xv[tr * 3 + tc] = (vy && (unsigned)ww < 64u) ? xc[(hh << 6) + ww] : 0.f;
            }
        }
        const float* wc = wofft + c * 243;
#pragma unroll
        for (int co = 0; co < 27; ++co)
#pragma unroll
            for (int k = 0; k < 9; ++k)
                acc[co] = fmaf(xv[k], wc[co * 9 + k], acc[co]);
    }
    float* omb = om + (size_t)b * 110592 + (h << 6) + w;
#pragma unroll
    for (int co = 0; co < 27; ++co)
        atomicAdd(&omb[co << 12], acc[co]);
}

// ---------------- bilinear coeff prep (packed: 4x u16 idx + 4x bf16 wgt) ------
__global__ __launch_bounds__(256) void k_prep_coeff(
    const float* __restrict__ om, uint4* __restrict__ cpk)
{
    int i = blockIdx.x * 256 + threadIdx.x;      // 294912
    int pix = i & 4095;
    int bk = i >> 12;
    int k = bk % 9;
    int b = bk / 9;
    int h = pix >> 6, w = pix & 63;
    const float* omb = om + (size_t)b * 110592;
    float dy = omb[(k << 12) + pix];
    float dx = omb[((9 + k) << 12) + pix];
    float mr = omb[((18 + k) << 12) + pix];
    float m  = 1.f / (1.f + __expf(-mr));
    float py = dy + (float)(k / 3 - 1 + h);
    float px = dx + (float)(k % 3 - 1 + w);
    float y0f = floorf(py), x0f = floorf(px);
    float wy = py - y0f, wx = px - x0f;
    int y0 = (int)y0f, x0 = (int)x0f;
    int y1 = y0 + 1, x1 = x0 + 1;
    float vy0 = ((unsigned)y0 < 64u) ? 1.f : 0.f;
    float vy1 = ((unsigned)y1 < 64u) ? 1.f : 0.f;
    float vx0 = ((unsigned)x0 < 64u) ? 1.f : 0.f;
    float vx1 = ((unsigned)x1 < 64u) ? 1.f : 0.f;
    int cy0 = min(max(y0, 0), 63), cy1 = min(max(y1, 0), 63);
    int cx0 = min(max(x0, 0), 63), cx1 = min(max(x1, 0), 63);
    u32 xw = (u32)((cy0 << 6) + cx0) | ((u32)((cy0 << 6) + cx1) << 16);
    u32 yw = (u32)((cy1 << 6) + cx0) | ((u32)((cy1 << 6) + cx1) << 16);
    float w00 = m * (1.f - wy) * (1.f - wx) * vy0 * vx0;
    float w01 = m * (1.f - wy) * wx         * vy0 * vx1;
    float w10 = m * wy         * (1.f - wx) * vy1 * vx0;
    float w11 = m * wy         * wx         * vy1 * vx1;
    u32 zw = bfr(w00) | (bfr(w01) << 16);
    u32 ww2 = bfr(w10) | (bfr(w11) << 16);
    cpk[i] = make_uint4(xw, yw, zw, ww2);
}

// ---------------- deform conv MFMA GEMM + BN1 + ReLU -> y ----------------
// No sA: A-frags loaded global->reg (prefetched one chunk ahead). LDS = sB x2.
// One barrier per K-chunk; gathers + A prefetch issued before MFMA.
__global__ __launch_bounds__(256, 2) void k_deform_mfma(
    const float* __restrict__ xt, const u16* __restrict__ Wdb,
    const uint4* __restrict__ cpk, const float* __restrict__ bnp,
    float* __restrict__ yout)
{
    __shared__ __align__(16) u16 sB[2][64 * 40];
    const int t = threadIdx.x;
    const int row = blockIdx.x & 63;
    const int b = blockIdx.x >> 6;               // grid 512
    const int pix0 = row << 6;
    const int p = t >> 2;        // gather pixel 0..63
    const int g = t & 3;         // c subgroup (8 channels each)
    const int g8 = g << 3;
    const float* xtb = xt + ((size_t)b << 20);   // [cc][4096][32]

    const int lane = t & 63;
    const int wv = t >> 6;
    const int quad = lane >> 4;
    const int ln = lane & 15;
    // per-thread A-frag base: row (wv*64 + mi*16 + ln), k-cols quad*8..+7
    const u16* Wrow = Wdb + (size_t)(wv * 64 + ln) * 32 + quad * 8;

    f32x4 acc[4][4];
#pragma unroll
    for (int i = 0; i < 4; ++i)
#pragma unroll
        for (int j = 0; j < 4; ++j) acc[i][j] = (f32x4)0.f;

    bf16x8 afb[2][4];
    uint4 qcur = cpk[(size_t)(b * 9) * 4096 + pix0 + p];
    {   // prologue: A frags + gather for ch=0 into parity 0
#pragma unroll
        for (int mi = 0; mi < 4; ++mi)
            afb[0][mi] = *(const bf16x8*)(Wrow + mi * 512);
        f32x4 ga[8];
        gather8(xtb, qcur, g8, ga);
        *(uint4*)&sB[0][p * 40 + g8] = packv(qcur, ga);
        __syncthreads();
    }

    for (int k = 0; k < 9; ++k) {
        uint4 qnext = qcur;
        if (k < 8) qnext = cpk[(size_t)(b * 9 + k + 1) * 4096 + pix0 + p];
#pragma unroll
        for (int cc = 0; cc < 8; ++cc) {
            const int ch = k * 8 + cc;
            const int par = cc & 1;
            const bool pre = ch < 71;
            const uint4 q = (cc == 7) ? qnext : qcur;   // static select (unrolled)
            f32x4 ga[8];
            if (pre) {
                // prefetch next A frags (coalesced 16B/lane from L2-hot Wdb)
                const u16* Wn = Wrow + (size_t)(ch + 1) * 8192;
#pragma unroll
                for (int mi = 0; mi < 4; ++mi)
                    afb[par ^ 1][mi] = *(const bf16x8*)(Wn + mi * 512);
                // issue next-iter gathers
                gather8(xtb + ((size_t)((cc + 1) & 7) << 17), q, g8, ga);
            }
            // MFMA on current parity
            bf16x8 bg[4];
#pragma unroll
            for (int i = 0; i < 4; ++i)
                bg[i] = *(const bf16x8*)&sB[par][(i * 16 + ln) * 40 + quad * 8];
#pragma unroll
            for (int mi = 0; mi < 4; ++mi)
#pragma unroll
                for (int ni = 0; ni < 4; ++ni)
                    acc[mi][ni] = __builtin_amdgcn_mfma_f32_16x16x32_bf16(
                        afb[par][mi], bg[ni], acc[mi][ni], 0, 0, 0);
            if (pre)
                *(uint4*)&sB[par ^ 1][p * 40 + g8] = packv(q, ga);
            __syncthreads();
        }
        qcur = qnext;
    }

    const float* sc1 = bnp;
    const float* bi1 = bnp + 256;
    float* yb2 = yout + ((size_t)b << 20);
#pragma unroll
    for (int mi = 0; mi < 4; ++mi) {
#pragma unroll
        for (int r = 0; r < 4; ++r) {
            int o = wv * 64 + mi * 16 + quad * 4 + r;
            float sc = sc1[o], bi = bi1[o];
#pragma unroll
            for (int ni = 0; ni < 4; ++ni) {
                float v = fmaxf(fmaf(acc[mi][ni][r], sc, bi), 0.f);
                yb2[((size_t)o << 12) + pix0 + ni * 16 + ln] = v;
            }
        }
    }
}

// ---------------- deconv MFMA GEMM + BN2 + ReLU -> up ----------------
// Barrier-free, LDS-free: A and B frags are direct contiguous 16B global
// loads; B from cg-planar yt => consecutive lanes contiguous (coalesced).
__global__ __launch_bounds__(256, 4) void k_deconv_mfma(
    const u16* __restrict__ yt, const u16* __restrict__ Wtb,
    const float* __restrict__ bnp, float* __restrict__ up)
{
    const int t = threadIdx.x;
    const int h0 = blockIdx.x & 63;
    const int cls = (blockIdx.x >> 6) & 3;
    const int b = blockIdx.x >> 8;               // grid 2048
    const int ca = cls >> 1, cb = cls & 1;
    const int DH0 = ca ? 0 : -1, DH1 = ca ? 1 : 0;
    const int DW0 = cb ? 0 : -1, DW1 = cb ? 1 : 0;

    const int lane = t & 63;
    const int wv = t >> 6;
    const int quad = lane >> 4;
    const int ln = lane & 15;

    // this thread's tap is its quad (K order = [tap][ci_l])
    const int DHq = (quad >> 1) ? DH1 : DH0;
    const int DWq = (quad & 1) ? DW1 : DW0;

    const u16* ytb = yt + (size_t)b * (32u * 4356 * 8);
    const u16* Bb[4];
#pragma unroll
    for (int i = 0; i < 4; ++i) {
        int pix = i * 16 + ln;
        Bb[i] = ytb + (size_t)((h0 + DHq + 1) * 66 + (pix + DWq + 1)) * 8;
    }
    const u16* Ab = Wtb + (size_t)(cls * 32) * 8192
                  + (size_t)(wv * 64 + ln) * 32 + quad * 8;

    f32x4 acc[4][4];
#pragma unroll
    for (int i = 0; i < 4; ++i)
#pragma unroll
        for (int j = 0; j < 4; ++j) acc[i][j] = (f32x4)0.f;

#pragma unroll 2
    for (int cc = 0; cc < 32; ++cc) {
        bf16x8 af[4], bg[4];
#pragma unroll
        for (int mi = 0; mi < 4; ++mi)
            af[mi] = *(const bf16x8*)(Ab + (size_t)cc * 8192 + mi * 512);
#pragma unroll
        for (int i = 0; i < 4; ++i)
            bg[i] = *(const bf16x8*)(Bb[i] + (size_t)cc * (4356 * 8));
#pragma unroll
        for (int mi = 0; mi < 4; ++mi)
#pragma unroll
            for (int ni = 0; ni < 4; ++ni)
                acc[mi][ni] = __builtin_amdgcn_mfma_f32_16x16x32_bf16(
                    af[mi], bg[ni], acc[mi][ni], 0, 0, 0);
    }

    const float* sc2 = bnp + 512;
    const float* bi2 = bnp + 768;
    float* ub = up + ((size_t)b << 22);
    const int pr = (h0 << 1) + ca;
#pragma unroll
    for (int mi = 0; mi < 4; ++mi) {
#pragma unroll
        for (int r = 0; r < 4; ++r) {
            int o = wv * 64 + mi * 16 + quad * 4 + r;
            float sc = sc2[o], bi = bi2[o];
#pragma unroll
            for (int ni = 0; ni < 4; ++ni) {
                int qc = ((ni * 16 + ln) << 1) + cb;
                float v = fmaxf(fmaf(acc[mi][ni][r], sc, bi), 0.f);
                ub[((size_t)o << 14) + (pr << 7) + qc] = v;
            }
        }
    }
}

extern "C" void kernel_launch(void* const* d_in, const int* in_sizes, int n_in,
                              void* d_out, int out_size, void* d_ws, size_t ws_size,
                              hipStream_t stream)
{
    const float* x     = (const float*)d_in[0];
    const float* w_off = (const float*)d_in[1];
    const float* b_off = (const float*)d_in[2];
    const float* w_dcn = (const float*)d_in[3];
    const float* g1    = (const float*)d_in[4];
    const float* be1   = (const float*)d_in[5];
    const float* mu1   = (const float*)d_in[6];
    const float* va1   = (const float*)d_in[7];
    const float* w_up  = (const float*)d_in[8];
    const float* g2    = (const float*)d_in[9];
    const float* be2   = (const float*)d_in[10];
    const float* mu2   = (const float*)d_in[11];
    const float* va2   = (const float*)d_in[12];

    float* yout = (float*)d_out;                 // 8*256*64*64
    float* up   = (float*)d_out + 8388608;       // 8*256*128*128
    // xt scratch lives in the 'up' region (33.5 MB of its 134 MB); consumed by
    // k_deform_mfma, later fully overwritten by k_deconv_mfma.
    float* xt   = up;

    // ws layout: region0 (0..17,842,176) holds phase-A buffers (om, wofft,
    // cpk, Wdb — all dead after k_deform_mfma), then is overlaid by yt
    // (cg-planar halo'd bf16 y) for phase B. Wtb+bnp live past both phases.
    char* ws = (char*)d_ws;
    float* om    = (float*)(ws + 0);             // 3,538,944 B
    float* wofft = (float*)(ws + 3538944);       //   248,832 B
    uint4* cpk   = (uint4*)(ws + 3787776);       // 4,718,592 B
    u16*   Wdb   = (u16*)  (ws + 8506368);       // 1,179,648 B -> ends 9,686,016
    u16*   yt    = (u16*)  (ws + 0);             // 17,842,176 B (phase B overlay)
    u16*   Wtb   = (u16*)  (ws + 17842176);      // 2,097,152 B
    float* bnp   = (float*)(ws + 19939328);      //     4,096 B
    // total ws: 19,943,424 B (~19.9 MB)

    k_tr_woff   <<<243,  256, 0, stream>>>(w_off, wofft);
    k_prep_wdb  <<<2304, 256, 0, stream>>>(w_dcn, Wdb);
    k_prep_wtb  <<<4096, 256, 0, stream>>>(w_up, Wtb);
    k_bn_prep   <<<1,    256, 0, stream>>>(g1, be1, mu1, va1, g2, be2, mu2, va2, bnp);
    k_om_init   <<<3456, 256, 0, stream>>>(b_off, om);
    k_tr_x      <<<1024, 256, 0, stream>>>(x, xt);
    k_offset_conv_part<<<1024, 256, 0, stream>>>(x, wofft, om);
    k_prep_coeff<<<1152, 256, 0, stream>>>(om, cpk);
    k_deform_mfma<<<512, 256, 0, stream>>>(xt, Wdb, cpk, bnp, yout);
    k_tr_y      <<<1152, 256, 0, stream>>>(yout, yt);
    k_deconv_mfma<<<2048,256, 0, stream>>>(yt, Wtb, bnp, up);
}

// Round 5
// 492.625 us; speedup vs baseline: 1.3012x; 1.1390x over previous
//
#include <hip/hip_runtime.h>
#include <cstddef>

// DeformLayer on MI355X. Round 8: offset conv -> MFMA. R7 counters: offset
// conv is top at 126us, MfmaUtil 0, VALU 23% (latency-bound fp32 stencil;
// VALU floor is 26us). Rewrite as 32x4096xK=2304 GEMM on matrix cores with
// split-bf16 precision (x=xh+xl, w=wh+wl; xh*wh+xl*wh+xh*wl => ~1e-5 offset
// accuracy, preserves fp32 numerics through floor()). B-frags are contiguous
// coalesced 16B loads from halo'd cg-planar xth (same layout trick as R7's
// deconv). Deletes k_offset_conv_part, k_om_init, k_tr_woff.
// deform/deconv/tr_x/tr_y/prep_coeff unchanged.

#define B_EPS 1e-5f

typedef __bf16 bf16x8 __attribute__((ext_vector_type(8)));
typedef float f32x4 __attribute__((ext_vector_type(4)));
typedef unsigned short u16;
typedef unsigned int u32;

__device__ __forceinline__ u32 bfr(float f) {          // fp32 -> bf16 bits (RNE)
    u32 u = __float_as_uint(f);
    return (u + 0x7FFFu + ((u >> 16) & 1u)) >> 16;
}

// gather 4 bilinear corners x 8 channels (2x f32x4 each) for one pixel/subgroup
__device__ __forceinline__ void gather8(const float* cb2, uint4 q, int g8, f32x4* ga) {
    const float* p00 = cb2 + ((size_t)(q.x & 0xFFFFu) << 5) + g8;
    const float* p01 = cb2 + ((size_t)(q.x >> 16) << 5) + g8;
    const float* p10 = cb2 + ((size_t)(q.y & 0xFFFFu) << 5) + g8;
    const float* p11 = cb2 + ((size_t)(q.y >> 16) << 5) + g8;
    ga[0] = *(const f32x4*)p00; ga[1] = *(const f32x4*)(p00 + 4);
    ga[2] = *(const f32x4*)p01; ga[3] = *(const f32x4*)(p01 + 4);
    ga[4] = *(const f32x4*)p10; ga[5] = *(const f32x4*)(p10 + 4);
    ga[6] = *(const f32x4*)p11; ga[7] = *(const f32x4*)(p11 + 4);
}

// combine corners with packed bf16 weights -> 8 bf16 values as uint4
__device__ __forceinline__ uint4 packv(uint4 q, const f32x4* ga) {
    const float w00 = __uint_as_float(q.z << 16);
    const float w01 = __uint_as_float(q.z & 0xFFFF0000u);
    const float w10 = __uint_as_float(q.w << 16);
    const float w11 = __uint_as_float(q.w & 0xFFFF0000u);
    union { bf16x8 h; uint4 u; } r;
#pragma unroll
    for (int jj = 0; jj < 4; ++jj) {
        r.h[jj]     = (__bf16)fmaf(w00, ga[0][jj], fmaf(w01, ga[2][jj], fmaf(w10, ga[4][jj], w11 * ga[6][jj])));
        r.h[4 + jj] = (__bf16)fmaf(w00, ga[1][jj], fmaf(w01, ga[3][jj], fmaf(w10, ga[5][jj], w11 * ga[7][jj])));
    }
    return r.u;
}

// ---------------- tiny prep kernels ----------------
// w_dcn[o][c][9] -> Wdb[ch][oc][32] bf16 (unpadded, frag-direct), ch = k*8+cc
__global__ __launch_bounds__(256) void k_prep_wdb(const float* __restrict__ w,
                                                  u16* __restrict__ o) {
    int i = blockIdx.x * 256 + threadIdx.x;      // 589824 = 2304*256
    int kk = i & 31; int e = i >> 5;
    int oc = e & 255; int ch = e >> 8;
    int cc = ch & 7; int k = ch >> 3;
    o[i] = (u16)bfr(w[oc * 2304 + (cc * 32 + kk) * 9 + k]);
}

// w_up[ci][co][wr][wc] -> Wtb[cls][cc][oc][32kk] bf16, kk = tap*8 + ci_l
__global__ __launch_bounds__(256) void k_prep_wtb(const float* __restrict__ w,
                                                  u16* __restrict__ o) {
    int i = blockIdx.x * 256 + threadIdx.x;      // 1048576 = 4096*256
    int kk = i & 31; int e = i >> 5;
    int oc = e & 255; e >>= 8;
    int cc = e & 31; int cls = e >> 5;
    int tap = kk >> 3, ci = cc * 8 + (kk & 7);
    int ca = cls >> 1, cb = cls & 1;
    int wr = (tap >> 1) ? (ca ? 0 : 1) : (ca ? 2 : 3);
    int wc = (tap & 1) ? (cb ? 0 : 1) : (cb ? 2 : 3);
    o[i] = (u16)bfr(w[ci * 4096 + oc * 16 + wr * 4 + wc]);
}

// w_off[27][256][9] -> Wob[ch=k*8+cc][part][32 oc][32 kk] bf16 split hi/lo
__global__ __launch_bounds__(256) void k_prep_wob(const float* __restrict__ w,
                                                  u16* __restrict__ o) {
    int i = blockIdx.x * 256 + threadIdx.x;      // 147456 = 576*256
    int kk = i & 31; int e = i >> 5;
    int oc = e & 31; e >>= 5;
    int part = e & 1; int ch = e >> 1;
    int cc = ch & 7, k = ch >> 3;
    float v = (oc < 27) ? w[oc * 2304 + (cc * 32 + kk) * 9 + k] : 0.f;
    u16 hh = bfr(v);
    if (part) {
        float vh = __uint_as_float((u32)hh << 16);
        hh = (u16)bfr(v - vh);
    }
    o[i] = hh;
}

// folded BN params: bnp = [sc1|bi1|sc2|bi2], 4x256 floats
__global__ __launch_bounds__(256) void k_bn_prep(
    const float* g1, const float* be1, const float* mu1, const float* va1,
    const float* g2, const float* be2, const float* mu2, const float* va2,
    float* bnp) {
    int t = threadIdx.x;
    float s1 = g1[t] * rsqrtf(va1[t] + B_EPS);
    bnp[t] = s1; bnp[256 + t] = be1[t] - mu1[t] * s1;
    float s2 = g2[t] * rsqrtf(va2[t] + B_EPS);
    bnp[512 + t] = s2; bnp[768 + t] = be2[t] - mu2[t] * s2;
}

// x[b][c][4096] -> xt[b][cc][pix][cl]  (fp32 chunk-NHWC, cc = c/32, cl = c%32)
__global__ __launch_bounds__(256) void k_tr_x(const float* __restrict__ x,
                                              float* __restrict__ xt) {
    const int t = threadIdx.x;
    const int pg = blockIdx.x & 15;              // 256-pixel group
    const int cc = (blockIdx.x >> 4) & 7;
    const int b = blockIdx.x >> 7;               // grid 1024
    const int pix = (pg << 8) + t;
    const float* xp = x + ((size_t)b << 20) + ((size_t)(cc << 5) << 12) + pix;
    float v[32];
#pragma unroll
    for (int cl = 0; cl < 32; ++cl) v[cl] = xp[(size_t)cl << 12];
    float* op = xt + ((size_t)b << 20) + ((size_t)cc << 17) + ((size_t)pix << 5);
#pragma unroll
    for (int i = 0; i < 8; ++i)
        *(f32x4*)(op + i * 4) = *(const f32x4*)&v[i * 4];
}

// x[b][c][4096] -> xth[b][part*32+cg][66*66][8] bf16 split hi/lo, halo zeros
__global__ __launch_bounds__(256) void k_prep_xth(const float* __restrict__ x,
                                                  u16* __restrict__ xo) {
    const int t = threadIdx.x;
    const int blk = blockIdx.x % 18;
    const int ccg = (blockIdx.x / 18) & 7;       // 32-ch group
    const int b = blockIdx.x / 144;              // grid 1152
    const int hp = blk * 256 + t;
    if (hp >= 4356) return;
    const int h = hp / 66, w = hp % 66;
    const size_t PL = 4356u * 8u;
    u16* dh = xo + ((size_t)b * 64 + ccg * 4) * PL + (size_t)hp * 8;
    u16* dl = dh + 32 * PL;
    if (h == 0 || h == 65 || w == 0 || w == 65) {
        uint4 z = make_uint4(0, 0, 0, 0);
#pragma unroll
        for (int j = 0; j < 4; ++j) {
            *(uint4*)(dh + (size_t)j * PL) = z;
            *(uint4*)(dl + (size_t)j * PL) = z;
        }
        return;
    }
    const float* xp = x + ((size_t)b << 20) + ((size_t)(ccg * 32) << 12)
                    + ((h - 1) << 6) + (w - 1);
    u16 vh[32], vl[32];
#pragma unroll
    for (int cl = 0; cl < 32; ++cl) {
        float v = xp[(size_t)cl << 12];
        u16 hh = (u16)bfr(v);
        vh[cl] = hh;
        vl[cl] = (u16)bfr(v - __uint_as_float((u32)hh << 16));
    }
#pragma unroll
    for (int j = 0; j < 4; ++j) {
        *(uint4*)(dh + (size_t)j * PL) = *(const uint4*)&vh[j * 8];
        *(uint4*)(dl + (size_t)j * PL) = *(const uint4*)&vl[j * 8];
    }
}

// y[b][o][4096] -> yt[b][cg=ci/8][66*66][8ci] bf16 halo-padded (zeros on border)
__global__ __launch_bounds__(256) void k_tr_y(const float* __restrict__ y,
                                              u16* __restrict__ yt) {
    const int t = threadIdx.x;
    const int blk = blockIdx.x % 18;
    const int oc = (blockIdx.x / 18) & 7;        // 32-ch group
    const int b = blockIdx.x / 144;              // grid 1152
    const int hp = blk * 256 + t;
    if (hp >= 4356) return;
    const int h = hp / 66, w = hp % 66;
    u16* dstb = yt + (((size_t)b * 32 + oc * 4) * 4356 + hp) * 8;
    if (h == 0 || h == 65 || w == 0 || w == 65) {
        uint4 z = make_uint4(0, 0, 0, 0);
#pragma unroll
        for (int j = 0; j < 4; ++j)
            *(uint4*)(dstb + (size_t)j * (4356 * 8)) = z;
        return;
    }
    const float* yp = y + ((size_t)b << 20) + ((size_t)(oc * 32) << 12)
                    + ((h - 1) << 6) + (w - 1);
    u16 vv[32];
#pragma unroll
    for (int cl = 0; cl < 32; ++cl) vv[cl] = (u16)bfr(yp[(size_t)cl << 12]);
#pragma unroll
    for (int j = 0; j < 4; ++j)
        *(uint4*)(dstb + (size_t)j * (4356 * 8)) = *(const uint4*)&vv[j * 8];
}

// ---------------- offset conv MFMA: om[b][27][4096] = conv(x,w_off)+b_off ----
// M=32 (27 padded), N=64 pixels (one row h0), K=2304 split 4 ways across
// waves (18 chunks each); split-bf16: acc = xh*wh + xl*wh + xh*wl.
// B-frags: contiguous coalesced 16B from halo'd cg-planar xth. LDS reduce.
__global__ __launch_bounds__(256, 2) void k_offset_mfma(
    const u16* __restrict__ xth, const u16* __restrict__ Wob,
    const float* __restrict__ b_off, float* __restrict__ om)
{
    __shared__ float sR[4][2048];
    const int t = threadIdx.x;
    const int h0 = blockIdx.x & 63;
    const int b = blockIdx.x >> 6;               // grid 512
    const int wv = t >> 6;
    const int lane = t & 63;
    const int quad = lane >> 4;
    const int ln = lane & 15;
    const size_t PL = 4356u * 8u;
    const u16* xbb = xth + (size_t)b * 64 * PL;

    f32x4 acc[2][4];
#pragma unroll
    for (int i = 0; i < 2; ++i)
#pragma unroll
        for (int j = 0; j < 4; ++j) acc[i][j] = (f32x4)0.f;

#pragma unroll 3
    for (int ci = 0; ci < 18; ++ci) {
        const int ch = wv * 18 + ci;
        const int k = ch >> 3, cc = ch & 7;
        const int dy = k / 3, dx = k - dy * 3;
        const int hp = (h0 + dy) * 66 + dx + ln;
        const u16* Bh = xbb + (size_t)((cc << 2) + quad) * PL + (size_t)hp * 8;
        const u16* Bl = Bh + 32 * PL;
        const u16* Ap = Wob + ch * 2048 + ln * 32 + (quad << 3);
        bf16x8 ah[2], al[2], bh[4], bl[4];
        ah[0] = *(const bf16x8*)(Ap);
        ah[1] = *(const bf16x8*)(Ap + 512);
        al[0] = *(const bf16x8*)(Ap + 1024);
        al[1] = *(const bf16x8*)(Ap + 1536);
#pragma unroll
        for (int ni = 0; ni < 4; ++ni) {
            bh[ni] = *(const bf16x8*)(Bh + ni * 128);
            bl[ni] = *(const bf16x8*)(Bl + ni * 128);
        }
#pragma unroll
        for (int mi = 0; mi < 2; ++mi)
#pragma unroll
            for (int ni = 0; ni < 4; ++ni) {
                acc[mi][ni] = __builtin_amdgcn_mfma_f32_16x16x32_bf16(
                    ah[mi], bh[ni], acc[mi][ni], 0, 0, 0);
                acc[mi][ni] = __builtin_amdgcn_mfma_f32_16x16x32_bf16(
                    al[mi], bh[ni], acc[mi][ni], 0, 0, 0);
                acc[mi][ni] = __builtin_amdgcn_mfma_f32_16x16x32_bf16(
                    ah[mi], bl[ni], acc[mi][ni], 0, 0, 0);
            }
    }

    // per-wave partials -> LDS (conflict-free: lanes stride 16B)
    float* sw = &sR[wv][0];
#pragma unroll
    for (int mi = 0; mi < 2; ++mi)
#pragma unroll
        for (int ni = 0; ni < 4; ++ni)
            *(f32x4*)&sw[((mi << 2) + ni) * 256 + (lane << 2)] = acc[mi][ni];
    __syncthreads();

    // final sum + bias + store om
#pragma unroll
    for (int j = 0; j < 8; ++j) {
        int flat = (t << 3) + j;
        int e = flat >> 8;                       // mi*4+ni
        int rem = flat & 255;
        int l2 = rem >> 2, r = rem & 3;
        int co = ((e >> 2) << 4) + ((l2 >> 4) << 2) + r;
        if (co < 27) {
            float s = sR[0][flat] + sR[1][flat] + sR[2][flat] + sR[3][flat];
            int w = ((e & 3) << 4) + (l2 & 15);
            om[(size_t)b * 110592 + ((size_t)co << 12) + (h0 << 6) + w]
                = s + b_off[co];
        }
    }
}

// ---------------- bilinear coeff prep (packed: 4x u16 idx + 4x bf16 wgt) ------
__global__ __launch_bounds__(256) void k_prep_coeff(
    const float* __restrict__ om, uint4* __restrict__ cpk)
{
    int i = blockIdx.x * 256 + threadIdx.x;      // 294912
    int pix = i & 4095;
    int bk = i >> 12;
    int k = bk % 9;
    int b = bk / 9;
    int h = pix >> 6, w = pix & 63;
    const float* omb = om + (size_t)b * 110592;
    float dy = omb[(k << 12) + pix];
    float dx = omb[((9 + k) << 12) + pix];
    float mr = omb[((18 + k) << 12) + pix];
    float m  = 1.f / (1.f + __expf(-mr));
    float py = dy + (float)(k / 3 - 1 + h);
    float px = dx + (float)(k % 3 - 1 + w);
    float y0f = floorf(py), x0f = floorf(px);
    float wy = py - y0f, wx = px - x0f;
    int y0 = (int)y0f, x0 = (int)x0f;
    int y1 = y0 + 1, x1 = x0 + 1;
    float vy0 = ((unsigned)y0 < 64u) ? 1.f : 0.f;
    float vy1 = ((unsigned)y1 < 64u) ? 1.f : 0.f;
    float vx0 = ((unsigned)x0 < 64u) ? 1.f : 0.f;
    float vx1 = ((unsigned)x1 < 64u) ? 1.f : 0.f;
    int cy0 = min(max(y0, 0), 63), cy1 = min(max(y1, 0), 63);
    int cx0 = min(max(x0, 0), 63), cx1 = min(max(x1, 0), 63);
    u32 xw = (u32)((cy0 << 6) + cx0) | ((u32)((cy0 << 6) + cx1) << 16);
    u32 yw = (u32)((cy1 << 6) + cx0) | ((u32)((cy1 << 6) + cx1) << 16);
    float w00 = m * (1.f - wy) * (1.f - wx) * vy0 * vx0;
    float w01 = m * (1.f - wy) * wx         * vy0 * vx1;
    float w10 = m * wy         * (1.f - wx) * vy1 * vx0;
    float w11 = m * wy         * wx         * vy1 * vx1;
    u32 zw = bfr(w00) | (bfr(w01) << 16);
    u32 ww2 = bfr(w10) | (bfr(w11) << 16);
    cpk[i] = make_uint4(xw, yw, zw, ww2);
}

// ---------------- deform conv MFMA GEMM + BN1 + ReLU -> y ----------------
// No sA: A-frags loaded global->reg (prefetched one chunk ahead). LDS = sB x2.
// One barrier per K-chunk; gathers + A prefetch issued before MFMA.
__global__ __launch_bounds__(256, 2) void k_deform_mfma(
    const float* __restrict__ xt, const u16* __restrict__ Wdb,
    const uint4* __restrict__ cpk, const float* __restrict__ bnp,
    float* __restrict__ yout)
{
    __shared__ __align__(16) u16 sB[2][64 * 40];
    const int t = threadIdx.x;
    const int row = blockIdx.x & 63;
    const int b = blockIdx.x >> 6;               // grid 512
    const int pix0 = row << 6;
    const int p = t >> 2;        // gather pixel 0..63
    const int g = t & 3;         // c subgroup (8 channels each)
    const int g8 = g << 3;
    const float* xtb = xt + ((size_t)b << 20);   // [cc][4096][32]

    const int lane = t & 63;
    const int wv = t >> 6;
    const int quad = lane >> 4;
    const int ln = lane & 15;
    // per-thread A-frag base: row (wv*64 + mi*16 + ln), k-cols quad*8..+7
    const u16* Wrow = Wdb + (size_t)(wv * 64 + ln) * 32 + quad * 8;

    f32x4 acc[4][4];
#pragma unroll
    for (int i = 0; i < 4; ++i)
#pragma unroll
        for (int j = 0; j < 4; ++j) acc[i][j] = (f32x4)0.f;

    bf16x8 afb[2][4];
    uint4 qcur = cpk[(size_t)(b * 9) * 4096 + pix0 + p];
    {   // prologue: A frags + gather for ch=0 into parity 0
#pragma unroll
        for (int mi = 0; mi < 4; ++mi)
            afb[0][mi] = *(const bf16x8*)(Wrow + mi * 512);
        f32x4 ga[8];
        gather8(xtb, qcur, g8, ga);
        *(uint4*)&sB[0][p * 40 + g8] = packv(qcur, ga);
        __syncthreads();
    }

    for (int k = 0; k < 9; ++k) {
        uint4 qnext = qcur;
        if (k < 8) qnext = cpk[(size_t)(b * 9 + k + 1) * 4096 + pix0 + p];
#pragma unroll
        for (int cc = 0; cc < 8; ++cc) {
            const int ch = k * 8 + cc;
            const int par = cc & 1;
            const bool pre = ch < 71;
            const uint4 q = (cc == 7) ? qnext : qcur;   // static select (unrolled)
            f32x4 ga[8];
            if (pre) {
                // prefetch next A frags (coalesced 16B/lane from L2-hot Wdb)
                const u16* Wn = Wrow + (size_t)(ch + 1) * 8192;
#pragma unroll
                for (int mi = 0; mi < 4; ++mi)
                    afb[par ^ 1][mi] = *(const bf16x8*)(Wn + mi * 512);
                // issue next-iter gathers
                gather8(xtb + ((size_t)((cc + 1) & 7) << 17), q, g8, ga);
            }
            // MFMA on current parity
            bf16x8 bg[4];
#pragma unroll
            for (int i = 0; i < 4; ++i)
                bg[i] = *(const bf16x8*)&sB[par][(i * 16 + ln) * 40 + quad * 8];
#pragma unroll
            for (int mi = 0; mi < 4; ++mi)
#pragma unroll
                for (int ni = 0; ni < 4; ++ni)
                    acc[mi][ni] = __builtin_amdgcn_mfma_f32_16x16x32_bf16(
                        afb[par][mi], bg[ni], acc[mi][ni], 0, 0, 0);
            if (pre)
                *(uint4*)&sB[par ^ 1][p * 40 + g8] = packv(q, ga);
            __syncthreads();
        }
        qcur = qnext;
    }

    const float* sc1 = bnp;
    const float* bi1 = bnp + 256;
    float* yb2 = yout + ((size_t)b << 20);
#pragma unroll
    for (int mi = 0; mi < 4; ++mi) {
#pragma unroll
        for (int r = 0; r < 4; ++r) {
            int o = wv * 64 + mi * 16 + quad * 4 + r;
            float sc = sc1[o], bi = bi1[o];
#pragma unroll
            for (int ni = 0; ni < 4; ++ni) {
                float v = fmaxf(fmaf(acc[mi][ni][r], sc, bi), 0.f);
                yb2[((size_t)o << 12) + pix0 + ni * 16 + ln] = v;
            }
        }
    }
}

// ---------------- deconv MFMA GEMM + BN2 + ReLU -> up ----------------
// Barrier-free, LDS-free: A and B frags are direct contiguous 16B global
// loads; B from cg-planar yt => consecutive lanes contiguous (coalesced).
__global__ __launch_bounds__(256, 4) void k_deconv_mfma(
    const u16* __restrict__ yt, const u16* __restrict__ Wtb,
    const float* __restrict__ bnp, float* __restrict__ up)
{
    const int t = threadIdx.x;
    const int h0 = blockIdx.x & 63;
    const int cls = (blockIdx.x >> 6) & 3;
    const int b = blockIdx.x >> 8;               // grid 2048
    const int ca = cls >> 1, cb = cls & 1;
    const int DH0 = ca ? 0 : -1, DH1 = ca ? 1 : 0;
    const int DW0 = cb ? 0 : -1, DW1 = cb ? 1 : 0;

    const int lane = t & 63;
    const int wv = t >> 6;
    const int quad = lane >> 4;
    const int ln = lane & 15;

    // this thread's tap is its quad (K order = [tap][ci_l])
    const int DHq = (quad >> 1) ? DH1 : DH0;
    const int DWq = (quad & 1) ? DW1 : DW0;

    const u16* ytb = yt + (size_t)b * (32u * 4356 * 8);
    const u16* Bb[4];
#pragma unroll
    for (int i = 0; i < 4; ++i) {
        int pix = i * 16 + ln;
        Bb[i] = ytb + (size_t)((h0 + DHq + 1) * 66 + (pix + DWq + 1)) * 8;
    }
    const u16* Ab = Wtb + (size_t)(cls * 32) * 8192
                  + (size_t)(wv * 64 + ln) * 32 + quad * 8;

    f32x4 acc[4][4];
#pragma unroll
    for (int i = 0; i < 4; ++i)
#pragma unroll
        for (int j = 0; j < 4; ++j) acc[i][j] = (f32x4)0.f;

#pragma unroll 2
    for (int cc = 0; cc < 32; ++cc) {
        bf16x8 af[4], bg[4];
#pragma unroll
        for (int mi = 0; mi < 4; ++mi)
            af[mi] = *(const bf16x8*)(Ab + (size_t)cc * 8192 + mi * 512);
#pragma unroll
        for (int i = 0; i < 4; ++i)
            bg[i] = *(const bf16x8*)(Bb[i] + (size_t)cc * (4356 * 8));
#pragma unroll
        for (int mi = 0; mi < 4; ++mi)
#pragma unroll
            for (int ni = 0; ni < 4; ++ni)
                acc[mi][ni] = __builtin_amdgcn_mfma_f32_16x16x32_bf16(
                    af[mi], bg[ni], acc[mi][ni], 0, 0, 0);
    }

    const float* sc2 = bnp + 512;
    const float* bi2 = bnp + 768;
    float* ub = up + ((size_t)b << 22);
    const int pr = (h0 << 1) + ca;
#pragma unroll
    for (int mi = 0; mi < 4; ++mi) {
#pragma unroll
        for (int r = 0; r < 4; ++r) {
            int o = wv * 64 + mi * 16 + quad * 4 + r;
            float sc = sc2[o], bi = bi2[o];
#pragma unroll
            for (int ni = 0; ni < 4; ++ni) {
                int qc = ((ni * 16 + ln) << 1) + cb;
                float v = fmaxf(fmaf(acc[mi][ni][r], sc, bi), 0.f);
                ub[((size_t)o << 14) + (pr << 7) + qc] = v;
            }
        }
    }
}

extern "C" void kernel_launch(void* const* d_in, const int* in_sizes, int n_in,
                              void* d_out, int out_size, void* d_ws, size_t ws_size,
                              hipStream_t stream)
{
    const float* x     = (const float*)d_in[0];
    const float* w_off = (const float*)d_in[1];
    const float* b_off = (const float*)d_in[2];
    const float* w_dcn = (const float*)d_in[3];
    const float* g1    = (const float*)d_in[4];
    const float* be1   = (const float*)d_in[5];
    const float* mu1   = (const float*)d_in[6];
    const float* va1   = (const float*)d_in[7];
    const float* w_up  = (const float*)d_in[8];
    const float* g2    = (const float*)d_in[9];
    const float* be2   = (const float*)d_in[10];
    const float* mu2   = (const float*)d_in[11];
    const float* va2   = (const float*)d_in[12];

    float* yout = (float*)d_out;                 // 8*256*64*64
    float* up   = (float*)d_out + 8388608;       // 8*256*128*128
    // up-region scratch (consumed before k_deconv_mfma writes up):
    //   xt  : fp32 chunk-NHWC x, 33,554,432 B at up+0
    //   xth : split-bf16 halo'd planar x, 35,684,352 B at up+33,554,432
    float* xt   = up;
    u16*   xth  = (u16*)((char*)up + 33554432);

    // ws layout: region0 holds phase-A buffers (om, cpk — dead after
    // k_prep_coeff/k_deform_mfma), overlaid by yt for phase B. Wob shares the
    // cpk region (consumed by k_offset_mfma before k_prep_coeff writes cpk).
    char* ws = (char*)d_ws;
    float* om    = (float*)(ws + 0);             // 3,538,944 B
    uint4* cpk   = (uint4*)(ws + 3787776);       // 4,718,592 B
    u16*   Wob   = (u16*)  (ws + 3787776);       //   294,912 B (pre-cpk overlay)
    u16*   Wdb   = (u16*)  (ws + 8506368);       // 1,179,648 B -> ends 9,686,016
    u16*   yt    = (u16*)  (ws + 0);             // 17,842,176 B (phase B overlay)
    u16*   Wtb   = (u16*)  (ws + 17842176);      // 2,097,152 B
    float* bnp   = (float*)(ws + 19939328);      //     4,096 B
    // total ws: 19,943,424 B (~19.9 MB)

    k_prep_wdb  <<<2304, 256, 0, stream>>>(w_dcn, Wdb);
    k_prep_wtb  <<<4096, 256, 0, stream>>>(w_up, Wtb);
    k_prep_wob  <<<576,  256, 0, stream>>>(w_off, Wob);
    k_bn_prep   <<<1,    256, 0, stream>>>(g1, be1, mu1, va1, g2, be2, mu2, va2, bnp);
    k_tr_x      <<<1024, 256, 0, stream>>>(x, xt);
    k_prep_xth  <<<1152, 256, 0, stream>>>(x, xth);
    k_offset_mfma<<<512, 256, 0, stream>>>(xth, Wob, b_off, om);
    k_prep_coeff<<<1152, 256, 0, stream>>>(om, cpk);
    k_deform_mfma<<<512, 256, 0, stream>>>(xt, Wdb, cpk, bnp, yout);
    k_tr_y      <<<1152, 256, 0, stream>>>(yout, yt);
    k_deconv_mfma<<<2048,256, 0, stream>>>(yt, Wtb, bnp, up);
}

// Round 6
// 488.801 us; speedup vs baseline: 1.3114x; 1.0078x over previous
//
#include <hip/hip_runtime.h>
#include <cstddef>

// DeformLayer on MI355X. Round 9: attack deconv latency (120us, MfmaUtil 23.5%,
// FETCH 50MB vs 20MB cold => L2 thrash from round-robin XCD assignment + no
// prefetch).
//  - T1 bijective XCD swizzle on deconv/deform/offset_mfma: contiguous lid
//    range per XCD => per-XCD working set ~4MB = L2-resident.
//  - deconv: depth-1 register double-buffer (prefetch cc+1 A/B frags before
//    cc's MFMA cluster), launch_bounds(256,3) for the +32 VGPR.
// Everything else unchanged from R8.

#define B_EPS 1e-5f

typedef __bf16 bf16x8 __attribute__((ext_vector_type(8)));
typedef float f32x4 __attribute__((ext_vector_type(4)));
typedef unsigned short u16;
typedef unsigned int u32;

__device__ __forceinline__ u32 bfr(float f) {          // fp32 -> bf16 bits (RNE)
    u32 u = __float_as_uint(f);
    return (u + 0x7FFFu + ((u >> 16) & 1u)) >> 16;
}

// gather 4 bilinear corners x 8 channels (2x f32x4 each) for one pixel/subgroup
__device__ __forceinline__ void gather8(const float* cb2, uint4 q, int g8, f32x4* ga) {
    const float* p00 = cb2 + ((size_t)(q.x & 0xFFFFu) << 5) + g8;
    const float* p01 = cb2 + ((size_t)(q.x >> 16) << 5) + g8;
    const float* p10 = cb2 + ((size_t)(q.y & 0xFFFFu) << 5) + g8;
    const float* p11 = cb2 + ((size_t)(q.y >> 16) << 5) + g8;
    ga[0] = *(const f32x4*)p00; ga[1] = *(const f32x4*)(p00 + 4);
    ga[2] = *(const f32x4*)p01; ga[3] = *(const f32x4*)(p01 + 4);
    ga[4] = *(const f32x4*)p10; ga[5] = *(const f32x4*)(p10 + 4);
    ga[6] = *(const f32x4*)p11; ga[7] = *(const f32x4*)(p11 + 4);
}

// combine corners with packed bf16 weights -> 8 bf16 values as uint4
__device__ __forceinline__ uint4 packv(uint4 q, const f32x4* ga) {
    const float w00 = __uint_as_float(q.z << 16);
    const float w01 = __uint_as_float(q.z & 0xFFFF0000u);
    const float w10 = __uint_as_float(q.w << 16);
    const float w11 = __uint_as_float(q.w & 0xFFFF0000u);
    union { bf16x8 h; uint4 u; } r;
#pragma unroll
    for (int jj = 0; jj < 4; ++jj) {
        r.h[jj]     = (__bf16)fmaf(w00, ga[0][jj], fmaf(w01, ga[2][jj], fmaf(w10, ga[4][jj], w11 * ga[6][jj])));
        r.h[4 + jj] = (__bf16)fmaf(w00, ga[1][jj], fmaf(w01, ga[3][jj], fmaf(w10, ga[5][jj], w11 * ga[7][jj])));
    }
    return r.u;
}

// ---------------- tiny prep kernels ----------------
// w_dcn[o][c][9] -> Wdb[ch][oc][32] bf16 (unpadded, frag-direct), ch = k*8+cc
__global__ __launch_bounds__(256) void k_prep_wdb(const float* __restrict__ w,
                                                  u16* __restrict__ o) {
    int i = blockIdx.x * 256 + threadIdx.x;      // 589824 = 2304*256
    int kk = i & 31; int e = i >> 5;
    int oc = e & 255; int ch = e >> 8;
    int cc = ch & 7; int k = ch >> 3;
    o[i] = (u16)bfr(w[oc * 2304 + (cc * 32 + kk) * 9 + k]);
}

// w_up[ci][co][wr][wc] -> Wtb[cls][cc][oc][32kk] bf16, kk = tap*8 + ci_l
__global__ __launch_bounds__(256) void k_prep_wtb(const float* __restrict__ w,
                                                  u16* __restrict__ o) {
    int i = blockIdx.x * 256 + threadIdx.x;      // 1048576 = 4096*256
    int kk = i & 31; int e = i >> 5;
    int oc = e & 255; e >>= 8;
    int cc = e & 31; int cls = e >> 5;
    int tap = kk >> 3, ci = cc * 8 + (kk & 7);
    int ca = cls >> 1, cb = cls & 1;
    int wr = (tap >> 1) ? (ca ? 0 : 1) : (ca ? 2 : 3);
    int wc = (tap & 1) ? (cb ? 0 : 1) : (cb ? 2 : 3);
    o[i] = (u16)bfr(w[ci * 4096 + oc * 16 + wr * 4 + wc]);
}

// w_off[27][256][9] -> Wob[ch=k*8+cc][part][32 oc][32 kk] bf16 split hi/lo
__global__ __launch_bounds__(256) void k_prep_wob(const float* __restrict__ w,
                                                  u16* __restrict__ o) {
    int i = blockIdx.x * 256 + threadIdx.x;      // 147456 = 576*256
    int kk = i & 31; int e = i >> 5;
    int oc = e & 31; e >>= 5;
    int part = e & 1; int ch = e >> 1;
    int cc = ch & 7, k = ch >> 3;
    float v = (oc < 27) ? w[oc * 2304 + (cc * 32 + kk) * 9 + k] : 0.f;
    u16 hh = bfr(v);
    if (part) {
        float vh = __uint_as_float((u32)hh << 16);
        hh = (u16)bfr(v - vh);
    }
    o[i] = hh;
}

// folded BN params: bnp = [sc1|bi1|sc2|bi2], 4x256 floats
__global__ __launch_bounds__(256) void k_bn_prep(
    const float* g1, const float* be1, const float* mu1, const float* va1,
    const float* g2, const float* be2, const float* mu2, const float* va2,
    float* bnp) {
    int t = threadIdx.x;
    float s1 = g1[t] * rsqrtf(va1[t] + B_EPS);
    bnp[t] = s1; bnp[256 + t] = be1[t] - mu1[t] * s1;
    float s2 = g2[t] * rsqrtf(va2[t] + B_EPS);
    bnp[512 + t] = s2; bnp[768 + t] = be2[t] - mu2[t] * s2;
}

// x[b][c][4096] -> xt[b][cc][pix][cl]  (fp32 chunk-NHWC, cc = c/32, cl = c%32)
__global__ __launch_bounds__(256) void k_tr_x(const float* __restrict__ x,
                                              float* __restrict__ xt) {
    const int t = threadIdx.x;
    const int pg = blockIdx.x & 15;              // 256-pixel group
    const int cc = (blockIdx.x >> 4) & 7;
    const int b = blockIdx.x >> 7;               // grid 1024
    const int pix = (pg << 8) + t;
    const float* xp = x + ((size_t)b << 20) + ((size_t)(cc << 5) << 12) + pix;
    float v[32];
#pragma unroll
    for (int cl = 0; cl < 32; ++cl) v[cl] = xp[(size_t)cl << 12];
    float* op = xt + ((size_t)b << 20) + ((size_t)cc << 17) + ((size_t)pix << 5);
#pragma unroll
    for (int i = 0; i < 8; ++i)
        *(f32x4*)(op + i * 4) = *(const f32x4*)&v[i * 4];
}

// x[b][c][4096] -> xth[b][part*32+cg][66*66][8] bf16 split hi/lo, halo zeros
__global__ __launch_bounds__(256) void k_prep_xth(const float* __restrict__ x,
                                                  u16* __restrict__ xo) {
    const int t = threadIdx.x;
    const int blk = blockIdx.x % 18;
    const int ccg = (blockIdx.x / 18) & 7;       // 32-ch group
    const int b = blockIdx.x / 144;              // grid 1152
    const int hp = blk * 256 + t;
    if (hp >= 4356) return;
    const int h = hp / 66, w = hp % 66;
    const size_t PL = 4356u * 8u;
    u16* dh = xo + ((size_t)b * 64 + ccg * 4) * PL + (size_t)hp * 8;
    u16* dl = dh + 32 * PL;
    if (h == 0 || h == 65 || w == 0 || w == 65) {
        uint4 z = make_uint4(0, 0, 0, 0);
#pragma unroll
        for (int j = 0; j < 4; ++j) {
            *(uint4*)(dh + (size_t)j * PL) = z;
            *(uint4*)(dl + (size_t)j * PL) = z;
        }
        return;
    }
    const float* xp = x + ((size_t)b << 20) + ((size_t)(ccg * 32) << 12)
                    + ((h - 1) << 6) + (w - 1);
    u16 vh[32], vl[32];
#pragma unroll
    for (int cl = 0; cl < 32; ++cl) {
        float v = xp[(size_t)cl << 12];
        u16 hh = (u16)bfr(v);
        vh[cl] = hh;
        vl[cl] = (u16)bfr(v - __uint_as_float((u32)hh << 16));
    }
#pragma unroll
    for (int j = 0; j < 4; ++j) {
        *(uint4*)(dh + (size_t)j * PL) = *(const uint4*)&vh[j * 8];
        *(uint4*)(dl + (size_t)j * PL) = *(const uint4*)&vl[j * 8];
    }
}

// y[b][o][4096] -> yt[b][cg=ci/8][66*66][8ci] bf16 halo-padded (zeros on border)
__global__ __launch_bounds__(256) void k_tr_y(const float* __restrict__ y,
                                              u16* __restrict__ yt) {
    const int t = threadIdx.x;
    const int blk = blockIdx.x % 18;
    const int oc = (blockIdx.x / 18) & 7;        // 32-ch group
    const int b = blockIdx.x / 144;              // grid 1152
    const int hp = blk * 256 + t;
    if (hp >= 4356) return;
    const int h = hp / 66, w = hp % 66;
    u16* dstb = yt + (((size_t)b * 32 + oc * 4) * 4356 + hp) * 8;
    if (h == 0 || h == 65 || w == 0 || w == 65) {
        uint4 z = make_uint4(0, 0, 0, 0);
#pragma unroll
        for (int j = 0; j < 4; ++j)
            *(uint4*)(dstb + (size_t)j * (4356 * 8)) = z;
        return;
    }
    const float* yp = y + ((size_t)b << 20) + ((size_t)(oc * 32) << 12)
                    + ((h - 1) << 6) + (w - 1);
    u16 vv[32];
#pragma unroll
    for (int cl = 0; cl < 32; ++cl) vv[cl] = (u16)bfr(yp[(size_t)cl << 12]);
#pragma unroll
    for (int j = 0; j < 4; ++j)
        *(uint4*)(dstb + (size_t)j * (4356 * 8)) = *(const uint4*)&vv[j * 8];
}

// ---------------- offset conv MFMA: om[b][27][4096] = conv(x,w_off)+b_off ----
__global__ __launch_bounds__(256, 2) void k_offset_mfma(
    const u16* __restrict__ xth, const u16* __restrict__ Wob,
    const float* __restrict__ b_off, float* __restrict__ om)
{
    __shared__ float sR[4][2048];
    const int t = threadIdx.x;
    const int bid = blockIdx.x;                  // grid 512, XCD swizzle
    const int lid = ((bid & 7) << 6) + (bid >> 3);
    const int h0 = lid & 63;
    const int b = lid >> 6;
    const int wv = t >> 6;
    const int lane = t & 63;
    const int quad = lane >> 4;
    const int ln = lane & 15;
    const size_t PL = 4356u * 8u;
    const u16* xbb = xth + (size_t)b * 64 * PL;

    f32x4 acc[2][4];
#pragma unroll
    for (int i = 0; i < 2; ++i)
#pragma unroll
        for (int j = 0; j < 4; ++j) acc[i][j] = (f32x4)0.f;

#pragma unroll 3
    for (int ci = 0; ci < 18; ++ci) {
        const int ch = wv * 18 + ci;
        const int k = ch >> 3, cc = ch & 7;
        const int dy = k / 3, dx = k - dy * 3;
        const int hp = (h0 + dy) * 66 + dx + ln;
        const u16* Bh = xbb + (size_t)((cc << 2) + quad) * PL + (size_t)hp * 8;
        const u16* Bl = Bh + 32 * PL;
        const u16* Ap = Wob + ch * 2048 + ln * 32 + (quad << 3);
        bf16x8 ah[2], al[2], bh[4], bl[4];
        ah[0] = *(const bf16x8*)(Ap);
        ah[1] = *(const bf16x8*)(Ap + 512);
        al[0] = *(const bf16x8*)(Ap + 1024);
        al[1] = *(const bf16x8*)(Ap + 1536);
#pragma unroll
        for (int ni = 0; ni < 4; ++ni) {
            bh[ni] = *(const bf16x8*)(Bh + ni * 128);
            bl[ni] = *(const bf16x8*)(Bl + ni * 128);
        }
#pragma unroll
        for (int mi = 0; mi < 2; ++mi)
#pragma unroll
            for (int ni = 0; ni < 4; ++ni) {
                acc[mi][ni] = __builtin_amdgcn_mfma_f32_16x16x32_bf16(
                    ah[mi], bh[ni], acc[mi][ni], 0, 0, 0);
                acc[mi][ni] = __builtin_amdgcn_mfma_f32_16x16x32_bf16(
                    al[mi], bh[ni], acc[mi][ni], 0, 0, 0);
                acc[mi][ni] = __builtin_amdgcn_mfma_f32_16x16x32_bf16(
                    ah[mi], bl[ni], acc[mi][ni], 0, 0, 0);
            }
    }

    // per-wave partials -> LDS (conflict-free: lanes stride 16B)
    float* sw = &sR[wv][0];
#pragma unroll
    for (int mi = 0; mi < 2; ++mi)
#pragma unroll
        for (int ni = 0; ni < 4; ++ni)
            *(f32x4*)&sw[((mi << 2) + ni) * 256 + (lane << 2)] = acc[mi][ni];
    __syncthreads();

    // final sum + bias + store om
#pragma unroll
    for (int j = 0; j < 8; ++j) {
        int flat = (t << 3) + j;
        int e = flat >> 8;                       // mi*4+ni
        int rem = flat & 255;
        int l2 = rem >> 2, r = rem & 3;
        int co = ((e >> 2) << 4) + ((l2 >> 4) << 2) + r;
        if (co < 27) {
            float s = sR[0][flat] + sR[1][flat] + sR[2][flat] + sR[3][flat];
            int w = ((e & 3) << 4) + (l2 & 15);
            om[(size_t)b * 110592 + ((size_t)co << 12) + (h0 << 6) + w]
                = s + b_off[co];
        }
    }
}

// ---------------- bilinear coeff prep (packed: 4x u16 idx + 4x bf16 wgt) ------
__global__ __launch_bounds__(256) void k_prep_coeff(
    const float* __restrict__ om, uint4* __restrict__ cpk)
{
    int i = blockIdx.x * 256 + threadIdx.x;      // 294912
    int pix = i & 4095;
    int bk = i >> 12;
    int k = bk % 9;
    int b = bk / 9;
    int h = pix >> 6, w = pix & 63;
    const float* omb = om + (size_t)b * 110592;
    float dy = omb[(k << 12) + pix];
    float dx = omb[((9 + k) << 12) + pix];
    float mr = omb[((18 + k) << 12) + pix];
    float m  = 1.f / (1.f + __expf(-mr));
    float py = dy + (float)(k / 3 - 1 + h);
    float px = dx + (float)(k % 3 - 1 + w);
    float y0f = floorf(py), x0f = floorf(px);
    float wy = py - y0f, wx = px - x0f;
    int y0 = (int)y0f, x0 = (int)x0f;
    int y1 = y0 + 1, x1 = x0 + 1;
    float vy0 = ((unsigned)y0 < 64u) ? 1.f : 0.f;
    float vy1 = ((unsigned)y1 < 64u) ? 1.f : 0.f;
    float vx0 = ((unsigned)x0 < 64u) ? 1.f : 0.f;
    float vx1 = ((unsigned)x1 < 64u) ? 1.f : 0.f;
    int cy0 = min(max(y0, 0), 63), cy1 = min(max(y1, 0), 63);
    int cx0 = min(max(x0, 0), 63), cx1 = min(max(x1, 0), 63);
    u32 xw = (u32)((cy0 << 6) + cx0) | ((u32)((cy0 << 6) + cx1) << 16);
    u32 yw = (u32)((cy1 << 6) + cx0) | ((u32)((cy1 << 6) + cx1) << 16);
    float w00 = m * (1.f - wy) * (1.f - wx) * vy0 * vx0;
    float w01 = m * (1.f - wy) * wx         * vy0 * vx1;
    float w10 = m * wy         * (1.f - wx) * vy1 * vx0;
    float w11 = m * wy         * wx         * vy1 * vx1;
    u32 zw = bfr(w00) | (bfr(w01) << 16);
    u32 ww2 = bfr(w10) | (bfr(w11) << 16);
    cpk[i] = make_uint4(xw, yw, zw, ww2);
}

// ---------------- deform conv MFMA GEMM + BN1 + ReLU -> y ----------------
// No sA: A-frags loaded global->reg (prefetched one chunk ahead). LDS = sB x2.
// One barrier per K-chunk; gathers + A prefetch issued before MFMA.
__global__ __launch_bounds__(256, 2) void k_deform_mfma(
    const float* __restrict__ xt, const u16* __restrict__ Wdb,
    const uint4* __restrict__ cpk, const float* __restrict__ bnp,
    float* __restrict__ yout)
{
    __shared__ __align__(16) u16 sB[2][64 * 40];
    const int t = threadIdx.x;
    const int bid = blockIdx.x;                  // grid 512, XCD swizzle
    const int lid = ((bid & 7) << 6) + (bid >> 3);
    const int row = lid & 63;
    const int b = lid >> 6;
    const int pix0 = row << 6;
    const int p = t >> 2;        // gather pixel 0..63
    const int g = t & 3;         // c subgroup (8 channels each)
    const int g8 = g << 3;
    const float* xtb = xt + ((size_t)b << 20);   // [cc][4096][32]

    const int lane = t & 63;
    const int wv = t >> 6;
    const int quad = lane >> 4;
    const int ln = lane & 15;
    // per-thread A-frag base: row (wv*64 + mi*16 + ln), k-cols quad*8..+7
    const u16* Wrow = Wdb + (size_t)(wv * 64 + ln) * 32 + quad * 8;

    f32x4 acc[4][4];
#pragma unroll
    for (int i = 0; i < 4; ++i)
#pragma unroll
        for (int j = 0; j < 4; ++j) acc[i][j] = (f32x4)0.f;

    bf16x8 afb[2][4];
    uint4 qcur = cpk[(size_t)(b * 9) * 4096 + pix0 + p];
    {   // prologue: A frags + gather for ch=0 into parity 0
#pragma unroll
        for (int mi = 0; mi < 4; ++mi)
            afb[0][mi] = *(const bf16x8*)(Wrow + mi * 512);
        f32x4 ga[8];
        gather8(xtb, qcur, g8, ga);
        *(uint4*)&sB[0][p * 40 + g8] = packv(qcur, ga);
        __syncthreads();
    }

    for (int k = 0; k < 9; ++k) {
        uint4 qnext = qcur;
        if (k < 8) qnext = cpk[(size_t)(b * 9 + k + 1) * 4096 + pix0 + p];
#pragma unroll
        for (int cc = 0; cc < 8; ++cc) {
            const int ch = k * 8 + cc;
            const int par = cc & 1;
            const bool pre = ch < 71;
            const uint4 q = (cc == 7) ? qnext : qcur;   // static select (unrolled)
            f32x4 ga[8];
            if (pre) {
                // prefetch next A frags (coalesced 16B/lane from L2-hot Wdb)
                const u16* Wn = Wrow + (size_t)(ch + 1) * 8192;
#pragma unroll
                for (int mi = 0; mi < 4; ++mi)
                    afb[par ^ 1][mi] = *(const bf16x8*)(Wn + mi * 512);
                // issue next-iter gathers
                gather8(xtb + ((size_t)((cc + 1) & 7) << 17), q, g8, ga);
            }
            // MFMA on current parity
            bf16x8 bg[4];
#pragma unroll
            for (int i = 0; i < 4; ++i)
                bg[i] = *(const bf16x8*)&sB[par][(i * 16 + ln) * 40 + quad * 8];
#pragma unroll
            for (int mi = 0; mi < 4; ++mi)
#pragma unroll
                for (int ni = 0; ni < 4; ++ni)
                    acc[mi][ni] = __builtin_amdgcn_mfma_f32_16x16x32_bf16(
                        afb[par][mi], bg[ni], acc[mi][ni], 0, 0, 0);
            if (pre)
                *(uint4*)&sB[par ^ 1][p * 40 + g8] = packv(q, ga);
            __syncthreads();
        }
        qcur = qnext;
    }

    const float* sc1 = bnp;
    const float* bi1 = bnp + 256;
    float* yb2 = yout + ((size_t)b << 20);
#pragma unroll
    for (int mi = 0; mi < 4; ++mi) {
#pragma unroll
        for (int r = 0; r < 4; ++r) {
            int o = wv * 64 + mi * 16 + quad * 4 + r;
            float sc = sc1[o], bi = bi1[o];
#pragma unroll
            for (int ni = 0; ni < 4; ++ni) {
                float v = fmaxf(fmaf(acc[mi][ni][r], sc, bi), 0.f);
                yb2[((size_t)o << 12) + pix0 + ni * 16 + ln] = v;
            }
        }
    }
}

// ---------------- deconv MFMA GEMM + BN2 + ReLU -> up ----------------
// Barrier-free, LDS-free; XCD-swizzled; depth-1 register double-buffer:
// prefetch cc+1's A/B frags (contiguous coalesced 16B) before cc's MFMAs.
__global__ __launch_bounds__(256, 3) void k_deconv_mfma(
    const u16* __restrict__ yt, const u16* __restrict__ Wtb,
    const float* __restrict__ bnp, float* __restrict__ up)
{
    const int t = threadIdx.x;
    const int bid = blockIdx.x;                  // grid 2048, XCD swizzle
    const int lid = ((bid & 7) << 8) + (bid >> 3);
    const int h0 = lid & 63;
    const int cls = (lid >> 6) & 3;
    const int b = lid >> 8;
    const int ca = cls >> 1, cb = cls & 1;
    const int DH0 = ca ? 0 : -1, DH1 = ca ? 1 : 0;
    const int DW0 = cb ? 0 : -1, DW1 = cb ? 1 : 0;

    const int lane = t & 63;
    const int wv = t >> 6;
    const int quad = lane >> 4;
    const int ln = lane & 15;

    // this thread's tap is its quad (K order = [tap][ci_l])
    const int DHq = (quad >> 1) ? DH1 : DH0;
    const int DWq = (quad & 1) ? DW1 : DW0;

    const u16* ytb = yt + (size_t)b * (32u * 4356 * 8);
    const u16* Bb[4];
#pragma unroll
    for (int i = 0; i < 4; ++i) {
        int pix = i * 16 + ln;
        Bb[i] = ytb + (size_t)((h0 + DHq + 1) * 66 + (pix + DWq + 1)) * 8;
    }
    const u16* Ab = Wtb + (size_t)(cls * 32) * 8192
                  + (size_t)(wv * 64 + ln) * 32 + quad * 8;

    f32x4 acc[4][4];
#pragma unroll
    for (int i = 0; i < 4; ++i)
#pragma unroll
        for (int j = 0; j < 4; ++j) acc[i][j] = (f32x4)0.f;

    bf16x8 af[2][4], bg[2][4];
#pragma unroll
    for (int mi = 0; mi < 4; ++mi)
        af[0][mi] = *(const bf16x8*)(Ab + mi * 512);
#pragma unroll
    for (int i = 0; i < 4; ++i)
        bg[0][i] = *(const bf16x8*)(Bb[i]);

#pragma unroll 2
    for (int cc = 0; cc < 32; ++cc) {
        const int par = cc & 1;                  // static under unroll-2
        if (cc < 31) {
#pragma unroll
            for (int mi = 0; mi < 4; ++mi)
                af[par ^ 1][mi] = *(const bf16x8*)(Ab + (size_t)(cc + 1) * 8192 + mi * 512);
#pragma unroll
            for (int i = 0; i < 4; ++i)
                bg[par ^ 1][i] = *(const bf16x8*)(Bb[i] + (size_t)(cc + 1) * (4356 * 8));
        }
#pragma unroll
        for (int mi = 0; mi < 4; ++mi)
#pragma unroll
            for (int ni = 0; ni < 4; ++ni)
                acc[mi][ni] = __builtin_amdgcn_mfma_f32_16x16x32_bf16(
                    af[par][mi], bg[par][ni], acc[mi][ni], 0, 0, 0);
    }

    const float* sc2 = bnp + 512;
    const float* bi2 = bnp + 768;
    float* ub = up + ((size_t)b << 22);
    const int pr = (h0 << 1) + ca;
#pragma unroll
    for (int mi = 0; mi < 4; ++mi) {
#pragma unroll
        for (int r = 0; r < 4; ++r) {
            int o = wv * 64 + mi * 16 + quad * 4 + r;
            float sc = sc2[o], bi = bi2[o];
#pragma unroll
            for (int ni = 0; ni < 4; ++ni) {
                int qc = ((ni * 16 + ln) << 1) + cb;
                float v = fmaxf(fmaf(acc[mi][ni][r], sc, bi), 0.f);
                ub[((size_t)o << 14) + (pr << 7) + qc] = v;
            }
        }
    }
}

extern "C" void kernel_launch(void* const* d_in, const int* in_sizes, int n_in,
                              void* d_out, int out_size, void* d_ws, size_t ws_size,
                              hipStream_t stream)
{
    const float* x     = (const float*)d_in[0];
    const float* w_off = (const float*)d_in[1];
    const float* b_off = (const float*)d_in[2];
    const float* w_dcn = (const float*)d_in[3];
    const float* g1    = (const float*)d_in[4];
    const float* be1   = (const float*)d_in[5];
    const float* mu1   = (const float*)d_in[6];
    const float* va1   = (const float*)d_in[7];
    const float* w_up  = (const float*)d_in[8];
    const float* g2    = (const float*)d_in[9];
    const float* be2   = (const float*)d_in[10];
    const float* mu2   = (const float*)d_in[11];
    const float* va2   = (const float*)d_in[12];

    float* yout = (float*)d_out;                 // 8*256*64*64
    float* up   = (float*)d_out + 8388608;       // 8*256*128*128
    // up-region scratch (consumed before k_deconv_mfma writes up):
    //   xt  : fp32 chunk-NHWC x, 33,554,432 B at up+0
    //   xth : split-bf16 halo'd planar x, 35,684,352 B at up+33,554,432
    float* xt   = up;
    u16*   xth  = (u16*)((char*)up + 33554432);

    // ws layout: region0 holds phase-A buffers (om, cpk — dead after
    // k_prep_coeff/k_deform_mfma), overlaid by yt for phase B. Wob shares the
    // cpk region (consumed by k_offset_mfma before k_prep_coeff writes cpk).
    char* ws = (char*)d_ws;
    float* om    = (float*)(ws + 0);             // 3,538,944 B
    uint4* cpk   = (uint4*)(ws + 3787776);       // 4,718,592 B
    u16*   Wob   = (u16*)  (ws + 3787776);       //   294,912 B (pre-cpk overlay)
    u16*   Wdb   = (u16*)  (ws + 8506368);       // 1,179,648 B -> ends 9,686,016
    u16*   yt    = (u16*)  (ws + 0);             // 17,842,176 B (phase B overlay)
    u16*   Wtb   = (u16*)  (ws + 17842176);      // 2,097,152 B
    float* bnp   = (float*)(ws + 19939328);      //     4,096 B
    // total ws: 19,943,424 B (~19.9 MB)

    k_prep_wdb  <<<2304, 256, 0, stream>>>(w_dcn, Wdb);
    k_prep_wtb  <<<4096, 256, 0, stream>>>(w_up, Wtb);
    k_prep_wob  <<<576,  256, 0, stream>>>(w_off, Wob);
    k_bn_prep   <<<1,    256, 0, stream>>>(g1, be1, mu1, va1, g2, be2, mu2, va2, bnp);
    k_tr_x      <<<1024, 256, 0, stream>>>(x, xt);
    k_prep_xth  <<<1152, 256, 0, stream>>>(x, xth);
    k_offset_mfma<<<512, 256, 0, stream>>>(xth, Wob, b_off, om);
    k_prep_coeff<<<1152, 256, 0, stream>>>(om, cpk);
    k_deform_mfma<<<512, 256, 0, stream>>>(xt, Wdb, cpk, bnp, yout);
    k_tr_y      <<<1152, 256, 0, stream>>>(yout, yt);
    k_deconv_mfma<<<2048,256, 0, stream>>>(yt, Wtb, bnp, up);
}

// Round 8
// 459.323 us; speedup vs baseline: 1.3956x; 1.0642x over previous
//
#include <hip/hip_runtime.h>
#include <cstddef>

// DeformLayer on MI355X. Round 10 (resubmit; R10 bench died to container infra
// failure, not kernel error): fix R9's deconv write-amplification.
// R9 counters: FETCH 50->36.5MB (XCD swizzle worked on reads) but WRITE
// 149->262MB = 2x|up|: the cb=0/cb=1 partner blocks write interleaved
// even/odd columns of the same cache lines; the swizzle moved partners 512
// bids apart -> lines evicted half-written -> 2x HBM writes. New ordering
// keeps batch-per-XCD but makes cls the fastest digit (partners adjacent,
// lines merge in L2). Also restore launch_bounds(256,4) (R9's ,3 cut
// occupancy 39->28%). Everything else unchanged from R9.

#define B_EPS 1e-5f

typedef __bf16 bf16x8 __attribute__((ext_vector_type(8)));
typedef float f32x4 __attribute__((ext_vector_type(4)));
typedef unsigned short u16;
typedef unsigned int u32;

__device__ __forceinline__ u32 bfr(float f) {          // fp32 -> bf16 bits (RNE)
    u32 u = __float_as_uint(f);
    return (u + 0x7FFFu + ((u >> 16) & 1u)) >> 16;
}

// gather 4 bilinear corners x 8 channels (2x f32x4 each) for one pixel/subgroup
__device__ __forceinline__ void gather8(const float* cb2, uint4 q, int g8, f32x4* ga) {
    const float* p00 = cb2 + ((size_t)(q.x & 0xFFFFu) << 5) + g8;
    const float* p01 = cb2 + ((size_t)(q.x >> 16) << 5) + g8;
    const float* p10 = cb2 + ((size_t)(q.y & 0xFFFFu) << 5) + g8;
    const float* p11 = cb2 + ((size_t)(q.y >> 16) << 5) + g8;
    ga[0] = *(const f32x4*)p00; ga[1] = *(const f32x4*)(p00 + 4);
    ga[2] = *(const f32x4*)p01; ga[3] = *(const f32x4*)(p01 + 4);
    ga[4] = *(const f32x4*)p10; ga[5] = *(const f32x4*)(p10 + 4);
    ga[6] = *(const f32x4*)p11; ga[7] = *(const f32x4*)(p11 + 4);
}

// combine corners with packed bf16 weights -> 8 bf16 values as uint4
__device__ __forceinline__ uint4 packv(uint4 q, const f32x4* ga) {
    const float w00 = __uint_as_float(q.z << 16);
    const float w01 = __uint_as_float(q.z & 0xFFFF0000u);
    const float w10 = __uint_as_float(q.w << 16);
    const float w11 = __uint_as_float(q.w & 0xFFFF0000u);
    union { bf16x8 h; uint4 u; } r;
#pragma unroll
    for (int jj = 0; jj < 4; ++jj) {
        r.h[jj]     = (__bf16)fmaf(w00, ga[0][jj], fmaf(w01, ga[2][jj], fmaf(w10, ga[4][jj], w11 * ga[6][jj])));
        r.h[4 + jj] = (__bf16)fmaf(w00, ga[1][jj], fmaf(w01, ga[3][jj], fmaf(w10, ga[5][jj], w11 * ga[7][jj])));
    }
    return r.u;
}

// ---------------- tiny prep kernels ----------------
// w_dcn[o][c][9] -> Wdb[ch][oc][32] bf16 (unpadded, frag-direct), ch = k*8+cc
__global__ __launch_bounds__(256) void k_prep_wdb(const float* __restrict__ w,
                                                  u16* __restrict__ o) {
    int i = blockIdx.x * 256 + threadIdx.x;      // 589824 = 2304*256
    int kk = i & 31; int e = i >> 5;
    int oc = e & 255; int ch = e >> 8;
    int cc = ch & 7; int k = ch >> 3;
    o[i] = (u16)bfr(w[oc * 2304 + (cc * 32 + kk) * 9 + k]);
}

// w_up[ci][co][wr][wc] -> Wtb[cls][cc][oc][32kk] bf16, kk = tap*8 + ci_l
__global__ __launch_bounds__(256) void k_prep_wtb(const float* __restrict__ w,
                                                  u16* __restrict__ o) {
    int i = blockIdx.x * 256 + threadIdx.x;      // 1048576 = 4096*256
    int kk = i & 31; int e = i >> 5;
    int oc = e & 255; e >>= 8;
    int cc = e & 31; int cls = e >> 5;
    int tap = kk >> 3, ci = cc * 8 + (kk & 7);
    int ca = cls >> 1, cb = cls & 1;
    int wr = (tap >> 1) ? (ca ? 0 : 1) : (ca ? 2 : 3);
    int wc = (tap & 1) ? (cb ? 0 : 1) : (cb ? 2 : 3);
    o[i] = (u16)bfr(w[ci * 4096 + oc * 16 + wr * 4 + wc]);
}

// w_off[27][256][9] -> Wob[ch=k*8+cc][part][32 oc][32 kk] bf16 split hi/lo
__global__ __launch_bounds__(256) void k_prep_wob(const float* __restrict__ w,
                                                  u16* __restrict__ o) {
    int i = blockIdx.x * 256 + threadIdx.x;      // 147456 = 576*256
    int kk = i & 31; int e = i >> 5;
    int oc = e & 31; e >>= 5;
    int part = e & 1; int ch = e >> 1;
    int cc = ch & 7, k = ch >> 3;
    float v = (oc < 27) ? w[oc * 2304 + (cc * 32 + kk) * 9 + k] : 0.f;
    u16 hh = bfr(v);
    if (part) {
        float vh = __uint_as_float((u32)hh << 16);
        hh = (u16)bfr(v - vh);
    }
    o[i] = hh;
}

// folded BN params: bnp = [sc1|bi1|sc2|bi2], 4x256 floats
__global__ __launch_bounds__(256) void k_bn_prep(
    const float* g1, const float* be1, const float* mu1, const float* va1,
    const float* g2, const float* be2, const float* mu2, const float* va2,
    float* bnp) {
    int t = threadIdx.x;
    float s1 = g1[t] * rsqrtf(va1[t] + B_EPS);
    bnp[t] = s1; bnp[256 + t] = be1[t] - mu1[t] * s1;
    float s2 = g2[t] * rsqrtf(va2[t] + B_EPS);
    bnp[512 + t] = s2; bnp[768 + t] = be2[t] - mu2[t] * s2;
}

// x[b][c][4096] -> xt[b][cc][pix][cl]  (fp32 chunk-NHWC, cc = c/32, cl = c%32)
__global__ __launch_bounds__(256) void k_tr_x(const float* __restrict__ x,
                                              float* __restrict__ xt) {
    const int t = threadIdx.x;
    const int pg = blockIdx.x & 15;              // 256-pixel group
    const int cc = (blockIdx.x >> 4) & 7;
    const int b = blockIdx.x >> 7;               // grid 1024
    const int pix = (pg << 8) + t;
    const float* xp = x + ((size_t)b << 20) + ((size_t)(cc << 5) << 12) + pix;
    float v[32];
#pragma unroll
    for (int cl = 0; cl < 32; ++cl) v[cl] = xp[(size_t)cl << 12];
    float* op = xt + ((size_t)b << 20) + ((size_t)cc << 17) + ((size_t)pix << 5);
#pragma unroll
    for (int i = 0; i < 8; ++i)
        *(f32x4*)(op + i * 4) = *(const f32x4*)&v[i * 4];
}

// x[b][c][4096] -> xth[b][part*32+cg][66*66][8] bf16 split hi/lo, halo zeros
__global__ __launch_bounds__(256) void k_prep_xth(const float* __restrict__ x,
                                                  u16* __restrict__ xo) {
    const int t = threadIdx.x;
    const int blk = blockIdx.x % 18;
    const int ccg = (blockIdx.x / 18) & 7;       // 32-ch group
    const int b = blockIdx.x / 144;              // grid 1152
    const int hp = blk * 256 + t;
    if (hp >= 4356) return;
    const int h = hp / 66, w = hp % 66;
    const size_t PL = 4356u * 8u;
    u16* dh = xo + ((size_t)b * 64 + ccg * 4) * PL + (size_t)hp * 8;
    u16* dl = dh + 32 * PL;
    if (h == 0 || h == 65 || w == 0 || w == 65) {
        uint4 z = make_uint4(0, 0, 0, 0);
#pragma unroll
        for (int j = 0; j < 4; ++j) {
            *(uint4*)(dh + (size_t)j * PL) = z;
            *(uint4*)(dl + (size_t)j * PL) = z;
        }
        return;
    }
    const float* xp = x + ((size_t)b << 20) + ((size_t)(ccg * 32) << 12)
                    + ((h - 1) << 6) + (w - 1);
    u16 vh[32], vl[32];
#pragma unroll
    for (int cl = 0; cl < 32; ++cl) {
        float v = xp[(size_t)cl << 12];
        u16 hh = (u16)bfr(v);
        vh[cl] = hh;
        vl[cl] = (u16)bfr(v - __uint_as_float((u32)hh << 16));
    }
#pragma unroll
    for (int j = 0; j < 4; ++j) {
        *(uint4*)(dh + (size_t)j * PL) = *(const uint4*)&vh[j * 8];
        *(uint4*)(dl + (size_t)j * PL) = *(const uint4*)&vl[j * 8];
    }
}

// y[b][o][4096] -> yt[b][cg=ci/8][66*66][8ci] bf16 halo-padded (zeros on border)
__global__ __launch_bounds__(256) void k_tr_y(const float* __restrict__ y,
                                              u16* __restrict__ yt) {
    const int t = threadIdx.x;
    const int blk = blockIdx.x % 18;
    const int oc = (blockIdx.x / 18) & 7;        // 32-ch group
    const int b = blockIdx.x / 144;              // grid 1152
    const int hp = blk * 256 + t;
    if (hp >= 4356) return;
    const int h = hp / 66, w = hp % 66;
    u16* dstb = yt + (((size_t)b * 32 + oc * 4) * 4356 + hp) * 8;
    if (h == 0 || h == 65 || w == 0 || w == 65) {
        uint4 z = make_uint4(0, 0, 0, 0);
#pragma unroll
        for (int j = 0; j < 4; ++j)
            *(uint4*)(dstb + (size_t)j * (4356 * 8)) = z;
        return;
    }
    const float* yp = y + ((size_t)b << 20) + ((size_t)(oc * 32) << 12)
                    + ((h - 1) << 6) + (w - 1);
    u16 vv[32];
#pragma unroll
    for (int cl = 0; cl < 32; ++cl) vv[cl] = (u16)bfr(yp[(size_t)cl << 12]);
#pragma unroll
    for (int j = 0; j < 4; ++j)
        *(uint4*)(dstb + (size_t)j * (4356 * 8)) = *(const uint4*)&vv[j * 8];
}

// ---------------- offset conv MFMA: om[b][27][4096] = conv(x,w_off)+b_off ----
__global__ __launch_bounds__(256, 2) void k_offset_mfma(
    const u16* __restrict__ xth, const u16* __restrict__ Wob,
    const float* __restrict__ b_off, float* __restrict__ om)
{
    __shared__ float sR[4][2048];
    const int t = threadIdx.x;
    const int bid = blockIdx.x;                  // grid 512, XCD swizzle
    const int lid = ((bid & 7) << 6) + (bid >> 3);
    const int h0 = lid & 63;
    const int b = lid >> 6;
    const int wv = t >> 6;
    const int lane = t & 63;
    const int quad = lane >> 4;
    const int ln = lane & 15;
    const size_t PL = 4356u * 8u;
    const u16* xbb = xth + (size_t)b * 64 * PL;

    f32x4 acc[2][4];
#pragma unroll
    for (int i = 0; i < 2; ++i)
#pragma unroll
        for (int j = 0; j < 4; ++j) acc[i][j] = (f32x4)0.f;

#pragma unroll 3
    for (int ci = 0; ci < 18; ++ci) {
        const int ch = wv * 18 + ci;
        const int k = ch >> 3, cc = ch & 7;
        const int dy = k / 3, dx = k - dy * 3;
        const int hp = (h0 + dy) * 66 + dx + ln;
        const u16* Bh = xbb + (size_t)((cc << 2) + quad) * PL + (size_t)hp * 8;
        const u16* Bl = Bh + 32 * PL;
        const u16* Ap = Wob + ch * 2048 + ln * 32 + (quad << 3);
        bf16x8 ah[2], al[2], bh[4], bl[4];
        ah[0] = *(const bf16x8*)(Ap);
        ah[1] = *(const bf16x8*)(Ap + 512);
        al[0] = *(const bf16x8*)(Ap + 1024);
        al[1] = *(const bf16x8*)(Ap + 1536);
#pragma unroll
        for (int ni = 0; ni < 4; ++ni) {
            bh[ni] = *(const bf16x8*)(Bh + ni * 128);
            bl[ni] = *(const bf16x8*)(Bl + ni * 128);
        }
#pragma unroll
        for (int mi = 0; mi < 2; ++mi)
#pragma unroll
            for (int ni = 0; ni < 4; ++ni) {
                acc[mi][ni] = __builtin_amdgcn_mfma_f32_16x16x32_bf16(
                    ah[mi], bh[ni], acc[mi][ni], 0, 0, 0);
                acc[mi][ni] = __builtin_amdgcn_mfma_f32_16x16x32_bf16(
                    al[mi], bh[ni], acc[mi][ni], 0, 0, 0);
                acc[mi][ni] = __builtin_amdgcn_mfma_f32_16x16x32_bf16(
                    ah[mi], bl[ni], acc[mi][ni], 0, 0, 0);
            }
    }

    // per-wave partials -> LDS (conflict-free: lanes stride 16B)
    float* sw = &sR[wv][0];
#pragma unroll
    for (int mi = 0; mi < 2; ++mi)
#pragma unroll
        for (int ni = 0; ni < 4; ++ni)
            *(f32x4*)&sw[((mi << 2) + ni) * 256 + (lane << 2)] = acc[mi][ni];
    __syncthreads();

    // final sum + bias + store om
#pragma unroll
    for (int j = 0; j < 8; ++j) {
        int flat = (t << 3) + j;
        int e = flat >> 8;                       // mi*4+ni
        int rem = flat & 255;
        int l2 = rem >> 2, r = rem & 3;
        int co = ((e >> 2) << 4) + ((l2 >> 4) << 2) + r;
        if (co < 27) {
            float s = sR[0][flat] + sR[1][flat] + sR[2][flat] + sR[3][flat];
            int w = ((e & 3) << 4) + (l2 & 15);
            om[(size_t)b * 110592 + ((size_t)co << 12) + (h0 << 6) + w]
                = s + b_off[co];
        }
    }
}

// ---------------- bilinear coeff prep (packed: 4x u16 idx + 4x bf16 wgt) ------
__global__ __launch_bounds__(256) void k_prep_coeff(
    const float* __restrict__ om, uint4* __restrict__ cpk)
{
    int i = blockIdx.x * 256 + threadIdx.x;      // 294912
    int pix = i & 4095;
    int bk = i >> 12;
    int k = bk % 9;
    int b = bk / 9;
    int h = pix >> 6, w = pix & 63;
    const float* omb = om + (size_t)b * 110592;
    float dy = omb[(k << 12) + pix];
    float dx = omb[((9 + k) << 12) + pix];
    float mr = omb[((18 + k) << 12) + pix];
    float m  = 1.f / (1.f + __expf(-mr));
    float py = dy + (float)(k / 3 - 1 + h);
    float px = dx + (float)(k % 3 - 1 + w);
    float y0f = floorf(py), x0f = floorf(px);
    float wy = py - y0f, wx = px - x0f;
    int y0 = (int)y0f, x0 = (int)x0f;
    int y1 = y0 + 1, x1 = x0 + 1;
    float vy0 = ((unsigned)y0 < 64u) ? 1.f : 0.f;
    float vy1 = ((unsigned)y1 < 64u) ? 1.f : 0.f;
    float vx0 = ((unsigned)x0 < 64u) ? 1.f : 0.f;
    float vx1 = ((unsigned)x1 < 64u) ? 1.f : 0.f;
    int cy0 = min(max(y0, 0), 63), cy1 = min(max(y1, 0), 63);
    int cx0 = min(max(x0, 0), 63), cx1 = min(max(x1, 0), 63);
    u32 xw = (u32)((cy0 << 6) + cx0) | ((u32)((cy0 << 6) + cx1) << 16);
    u32 yw = (u32)((cy1 << 6) + cx0) | ((u32)((cy1 << 6) + cx1) << 16);
    float w00 = m * (1.f - wy) * (1.f - wx) * vy0 * vx0;
    float w01 = m * (1.f - wy) * wx         * vy0 * vx1;
    float w10 = m * wy         * (1.f - wx) * vy1 * vx0;
    float w11 = m * wy         * wx         * vy1 * vx1;
    u32 zw = bfr(w00) | (bfr(w01) << 16);
    u32 ww2 = bfr(w10) | (bfr(w11) << 16);
    cpk[i] = make_uint4(xw, yw, zw, ww2);
}

// ---------------- deform conv MFMA GEMM + BN1 + ReLU -> y ----------------
// No sA: A-frags loaded global->reg (prefetched one chunk ahead). LDS = sB x2.
// One barrier per K-chunk; gathers + A prefetch issued before MFMA.
__global__ __launch_bounds__(256, 2) void k_deform_mfma(
    const float* __restrict__ xt, const u16* __restrict__ Wdb,
    const uint4* __restrict__ cpk, const float* __restrict__ bnp,
    float* __restrict__ yout)
{
    __shared__ __align__(16) u16 sB[2][64 * 40];
    const int t = threadIdx.x;
    const int bid = blockIdx.x;                  // grid 512, XCD swizzle
    const int lid = ((bid & 7) << 6) + (bid >> 3);
    const int row = lid & 63;
    const int b = lid >> 6;
    const int pix0 = row << 6;
    const int p = t >> 2;        // gather pixel 0..63
    const int g = t & 3;         // c subgroup (8 channels each)
    const int g8 = g << 3;
    const float* xtb = xt + ((size_t)b << 20);   // [cc][4096][32]

    const int lane = t & 63;
    const int wv = t >> 6;
    const int quad = lane >> 4;
    const int ln = lane & 15;
    // per-thread A-frag base: row (wv*64 + mi*16 + ln), k-cols quad*8..+7
    const u16* Wrow = Wdb + (size_t)(wv * 64 + ln) * 32 + quad * 8;

    f32x4 acc[4][4];
#pragma unroll
    for (int i = 0; i < 4; ++i)
#pragma unroll
        for (int j = 0; j < 4; ++j) acc[i][j] = (f32x4)0.f;

    bf16x8 afb[2][4];
    uint4 qcur = cpk[(size_t)(b * 9) * 4096 + pix0 + p];
    {   // prologue: A frags + gather for ch=0 into parity 0
#pragma unroll
        for (int mi = 0; mi < 4; ++mi)
            afb[0][mi] = *(const bf16x8*)(Wrow + mi * 512);
        f32x4 ga[8];
        gather8(xtb, qcur, g8, ga);
        *(uint4*)&sB[0][p * 40 + g8] = packv(qcur, ga);
        __syncthreads();
    }

    for (int k = 0; k < 9; ++k) {
        uint4 qnext = qcur;
        if (k < 8) qnext = cpk[(size_t)(b * 9 + k + 1) * 4096 + pix0 + p];
#pragma unroll
        for (int cc = 0; cc < 8; ++cc) {
            const int ch = k * 8 + cc;
            const int par = cc & 1;
            const bool pre = ch < 71;
            const uint4 q = (cc == 7) ? qnext : qcur;   // static select (unrolled)
            f32x4 ga[8];
            if (pre) {
                // prefetch next A frags (coalesced 16B/lane from L2-hot Wdb)
                const u16* Wn = Wrow + (size_t)(ch + 1) * 8192;
#pragma unroll
                for (int mi = 0; mi < 4; ++mi)
                    afb[par ^ 1][mi] = *(const bf16x8*)(Wn + mi * 512);
                // issue next-iter gathers
                gather8(xtb + ((size_t)((cc + 1) & 7) << 17), q, g8, ga);
            }
            // MFMA on current parity
            bf16x8 bg[4];
#pragma unroll
            for (int i = 0; i < 4; ++i)
                bg[i] = *(const bf16x8*)&sB[par][(i * 16 + ln) * 40 + quad * 8];
#pragma unroll
            for (int mi = 0; mi < 4; ++mi)
#pragma unroll
                for (int ni = 0; ni < 4; ++ni)
                    acc[mi][ni] = __builtin_amdgcn_mfma_f32_16x16x32_bf16(
                        afb[par][mi], bg[ni], acc[mi][ni], 0, 0, 0);
            if (pre)
                *(uint4*)&sB[par ^ 1][p * 40 + g8] = packv(q, ga);
            __syncthreads();
        }
        qcur = qnext;
    }

    const float* sc1 = bnp;
    const float* bi1 = bnp + 256;
    float* yb2 = yout + ((size_t)b << 20);
#pragma unroll
    for (int mi = 0; mi < 4; ++mi) {
#pragma unroll
        for (int r = 0; r < 4; ++r) {
            int o = wv * 64 + mi * 16 + quad * 4 + r;
            float sc = sc1[o], bi = bi1[o];
#pragma unroll
            for (int ni = 0; ni < 4; ++ni) {
                float v = fmaxf(fmaf(acc[mi][ni][r], sc, bi), 0.f);
                yb2[((size_t)o << 12) + pix0 + ni * 16 + ln] = v;
            }
        }
    }
}

// ---------------- deconv MFMA GEMM + BN2 + ReLU -> up ----------------
// Barrier-free, LDS-free; batch-per-XCD swizzle with cls fastest (write
// partners adjacent -> L2 line merge); depth-1 register double-buffer.
__global__ __launch_bounds__(256, 4) void k_deconv_mfma(
    const u16* __restrict__ yt, const u16* __restrict__ Wtb,
    const float* __restrict__ bnp, float* __restrict__ up)
{
    const int t = threadIdx.x;
    const int bid = blockIdx.x;                  // grid 2048
    const int b = bid & 7;                       // one batch per XCD
    const int local = bid >> 3;                  // 0..255 within XCD
    const int h0 = local >> 2;
    const int cls = local & 3;                   // cls fastest: cb partners adjacent
    const int ca = cls >> 1, cb = cls & 1;
    const int DH0 = ca ? 0 : -1, DH1 = ca ? 1 : 0;
    const int DW0 = cb ? 0 : -1, DW1 = cb ? 1 : 0;

    const int lane = t & 63;
    const int wv = t >> 6;
    const int quad = lane >> 4;
    const int ln = lane & 15;

    // this thread's tap is its quad (K order = [tap][ci_l])
    const int DHq = (quad >> 1) ? DH1 : DH0;
    const int DWq = (quad & 1) ? DW1 : DW0;

    const u16* ytb = yt + (size_t)b * (32u * 4356 * 8);
    const u16* Bb[4];
#pragma unroll
    for (int i = 0; i < 4; ++i) {
        int pix = i * 16 + ln;
        Bb[i] = ytb + (size_t)((h0 + DHq + 1) * 66 + (pix + DWq + 1)) * 8;
    }
    const u16* Ab = Wtb + (size_t)(cls * 32) * 8192
                  + (size_t)(wv * 64 + ln) * 32 + quad * 8;

    f32x4 acc[4][4];
#pragma unroll
    for (int i = 0; i < 4; ++i)
#pragma unroll
        for (int j = 0; j < 4; ++j) acc[i][j] = (f32x4)0.f;

    bf16x8 af[2][4], bg[2][4];
#pragma unroll
    for (int mi = 0; mi < 4; ++mi)
        af[0][mi] = *(const bf16x8*)(Ab + mi * 512);
#pragma unroll
    for (int i = 0; i < 4; ++i)
        bg[0][i] = *(const bf16x8*)(Bb[i]);

#pragma unroll 2
    for (int cc = 0; cc < 32; ++cc) {
        const int par = cc & 1;                  // static under unroll-2
        if (cc < 31) {
#pragma unroll
            for (int mi = 0; mi < 4; ++mi)
                af[par ^ 1][mi] = *(const bf16x8*)(Ab + (size_t)(cc + 1) * 8192 + mi * 512);
#pragma unroll
            for (int i = 0; i < 4; ++i)
                bg[par ^ 1][i] = *(const bf16x8*)(Bb[i] + (size_t)(cc + 1) * (4356 * 8));
        }
#pragma unroll
        for (int mi = 0; mi < 4; ++mi)
#pragma unroll
            for (int ni = 0; ni < 4; ++ni)
                acc[mi][ni] = __builtin_amdgcn_mfma_f32_16x16x32_bf16(
                    af[par][mi], bg[par][ni], acc[mi][ni], 0, 0, 0);
    }

    const float* sc2 = bnp + 512;
    const float* bi2 = bnp + 768;
    float* ub = up + ((size_t)b << 22);
    const int pr = (h0 << 1) + ca;
#pragma unroll
    for (int mi = 0; mi < 4; ++mi) {
#pragma unroll
        for (int r = 0; r < 4; ++r) {
            int o = wv * 64 + mi * 16 + quad * 4 + r;
            float sc = sc2[o], bi = bi2[o];
#pragma unroll
            for (int ni = 0; ni < 4; ++ni) {
                int qc = ((ni * 16 + ln) << 1) + cb;
                float v = fmaxf(fmaf(acc[mi][ni][r], sc, bi), 0.f);
                ub[((size_t)o << 14) + (pr << 7) + qc] = v;
            }
        }
    }
}

extern "C" void kernel_launch(void* const* d_in, const int* in_sizes, int n_in,
                              void* d_out, int out_size, void* d_ws, size_t ws_size,
                              hipStream_t stream)
{
    const float* x     = (const float*)d_in[0];
    const float* w_off = (const float*)d_in[1];
    const float* b_off = (const float*)d_in[2];
    const float* w_dcn = (const float*)d_in[3];
    const float* g1    = (const float*)d_in[4];
    const float* be1   = (const float*)d_in[5];
    const float* mu1   = (const float*)d_in[6];
    const float* va1   = (const float*)d_in[7];
    const float* w_up  = (const float*)d_in[8];
    const float* g2    = (const float*)d_in[9];
    const float* be2   = (const float*)d_in[10];
    const float* mu2   = (const float*)d_in[11];
    const float* va2   = (const float*)d_in[12];

    float* yout = (float*)d_out;                 // 8*256*64*64
    float* up   = (float*)d_out + 8388608;       // 8*256*128*128
    // up-region scratch (consumed before k_deconv_mfma writes up):
    //   xt  : fp32 chunk-NHWC x, 33,554,432 B at up+0
    //   xth : split-bf16 halo'd planar x, 35,684,352 B at up+33,554,432
    float* xt   = up;
    u16*   xth  = (u16*)((char*)up + 33554432);

    // ws layout: region0 holds phase-A buffers (om, cpk — dead after
    // k_prep_coeff/k_deform_mfma), overlaid by yt for phase B. Wob shares the
    // cpk region (consumed by k_offset_mfma before k_prep_coeff writes cpk).
    char* ws = (char*)d_ws;
    float* om    = (float*)(ws + 0);             // 3,538,944 B
    uint4* cpk   = (uint4*)(ws + 3787776);       // 4,718,592 B
    u16*   Wob   = (u16*)  (ws + 3787776);       //   294,912 B (pre-cpk overlay)
    u16*   Wdb   = (u16*)  (ws + 8506368);       // 1,179,648 B -> ends 9,686,016
    u16*   yt    = (u16*)  (ws + 0);             // 17,842,176 B (phase B overlay)
    u16*   Wtb   = (u16*)  (ws + 17842176);      // 2,097,152 B
    float* bnp   = (float*)(ws + 19939328);      //     4,096 B
    // total ws: 19,943,424 B (~19.9 MB)

    k_prep_wdb  <<<2304, 256, 0, stream>>>(w_dcn, Wdb);
    k_prep_wtb  <<<4096, 256, 0, stream>>>(w_up, Wtb);
    k_prep_wob  <<<576,  256, 0, stream>>>(w_off, Wob);
    k_bn_prep   <<<1,    256, 0, stream>>>(g1, be1, mu1, va1, g2, be2, mu2, va2, bnp);
    k_tr_x      <<<1024, 256, 0, stream>>>(x, xt);
    k_prep_xth  <<<1152, 256, 0, stream>>>(x, xth);
    k_offset_mfma<<<512, 256, 0, stream>>>(xth, Wob, b_off, om);
    k_prep_coeff<<<1152, 256, 0, stream>>>(om, cpk);
    k_deform_mfma<<<512, 256, 0, stream>>>(xt, Wdb, cpk, bnp, yout);
    k_tr_y      <<<1152, 256, 0, stream>>>(yout, yt);
    k_deconv_mfma<<<2048,256, 0, stream>>>(yt, Wtb, bnp, up);
}